// Round 4
// baseline (330.113 us; speedup 1.0000x reference)
//
#include <hip/hip_runtime.h>
#include <hip/hip_bf16.h>

#define B_SZ 512
#define KHOP 2
#define NNB  32
#define F0   512
#define C1   4
#define F1   16
#define C2   32
#define NCLS 40

#define EPS_BN   1e-5f
#define EPS_NORM 1e-7f

typedef __attribute__((ext_vector_type(8))) short short8;
typedef __attribute__((ext_vector_type(4))) float f32x4;

__device__ __forceinline__ float softsignf(float v) { return v / (1.0f + fabsf(v)); }

// HW packed f32->bf16 (RNE). lo -> bits[15:0], hi -> bits[31:16].
__device__ __forceinline__ unsigned cvt_pk_bf16(float lo, float hi) {
    unsigned r;
    asm("v_cvt_pk_bf16_f32 %0, %1, %2" : "=v"(r) : "v"(lo), "v"(hi));
    return r;
}

// ---------------------------------------------------------------------------
// Prep: W1 (K,C1,1,F0,F1) fp32 -> w1t bf16 [k][de=d*16+e][g]  (contiguous
// 16B B-frags for phase-3 MFMA, served from L2).
// ---------------------------------------------------------------------------
__global__ __launch_bounds__(256) void k_prep(const float* __restrict__ W1,
                                              unsigned short* __restrict__ w1t)
{
    const int idx = blockIdx.x * 256 + threadIdx.x;   // [0, 65536)
    const int g  = idx & 511;
    const int de = (idx >> 9) & 63;
    const int kk = idx >> 15;
    const int d = de >> 4, e = de & 15;
    w1t[idx] = (unsigned short)cvt_pk_bf16(W1[((size_t)((kk * 4 + d) * 512) + g) * 16 + e], 0.f);
}

// ---------------------------------------------------------------------------
// Kernel 1 (per (b,k) block, 256 thr): MFMA-based, LDS-slim (36 KiB -> 3+ blk/CU).
// LDS layout:
//   [0,32768)      Vt strip bf16 [512 g][32 f], byte = g*64 + (2f ^ (((g>>1)&3)<<4))
//                  - transient: staging s-partials fp32 [4][512] (first 8 KiB)
//                  - after GEMM1: A' bf16 [32 n][512 g], byte = n*1024 + (2g ^ ((n&7)<<4))
//   [32768,34816)  xl fp32[512]  -> xgx fp32[512] after V-loop
//   [34816,36864)  sl fp32[512]  -> invD fp32[512] after V-loop
// A (nb) is NOT staged: GEMM1 A-frags stream from global (L2-hot 64KB tile).
// ---------------------------------------------------------------------------
#define SMEM_MAIN 36864

__global__ __launch_bounds__(256, 3) void k_main(
    const float* __restrict__ xg_, const float* __restrict__ nbg,
    const unsigned short* __restrict__ w1t,
    const float* __restrict__ g1, const float* __restrict__ b1,
    float* __restrict__ h_raw, float* __restrict__ nbs_out,
    float* __restrict__ hsum)
{
    extern __shared__ char smem[];
    float* xl = (float*)(smem + 32768);   // x, later xgx
    float* sl = (float*)(smem + 34816);   // s, later invD

    const int t = threadIdx.x;
    const int pair = blockIdx.x;          // b*2 + k
    const int b = pair >> 1, k = pair & 1;
    const int l = t & 63, w = t >> 6;
    const float* nbp = nbg + (size_t)pair * (NNB * F0);

    // ---- phase 0: one pass over nb for s[f]; load x ----
    {
        const int oct = t & 63, ng = t >> 6;
        const int f0s = oct * 8;
        float sp0=0,sp1=0,sp2=0,sp3=0,sp4=0,sp5=0,sp6=0,sp7=0;
        #pragma unroll
        for (int ni = 0; ni < 8; ++ni) {
            const int n = ng * 8 + ni;
            float4 q0 = *(const float4*)(nbp + n * F0 + f0s);
            float4 q1 = *(const float4*)(nbp + n * F0 + f0s + 4);
            sp0 += q0.x; sp1 += q0.y; sp2 += q0.z; sp3 += q0.w;
            sp4 += q1.x; sp5 += q1.y; sp6 += q1.z; sp7 += q1.w;
        }
        float* part = (float*)smem;
        *(float4*)(part + ng * 512 + f0s)     = make_float4(sp0, sp1, sp2, sp3);
        *(float4*)(part + ng * 512 + f0s + 4) = make_float4(sp4, sp5, sp6, sp7);
        xl[t]       = xg_[b * F0 + t];
        xl[t + 256] = xg_[b * F0 + t + 256];
    }
    __syncthreads();
    {
        const float* part = (const float*)smem;
        sl[t]       = part[t] + part[512 + t] + part[1024 + t] + part[1536 + t];
        sl[t + 256] = part[t + 256] + part[512 + t + 256]
                    + part[1024 + t + 256] + part[1536 + t + 256];
    }
    __syncthreads();

    // per-thread owned columns
    const int gA = t, gB = t + 256;
    const float xa = xl[gA], xb = xl[gB];
    const float sa = sl[gA], sb = sl[gB];
    float dA0=0.f, dA1=0.f, dB0=0.f, dB1=0.f;
    float xA0=0.f, xA1=0.f, xB0=0.f, xB1=0.f;

    f32x4 acc[2][8];
    #pragma unroll
    for (int m = 0; m < 2; ++m)
        #pragma unroll
        for (int j = 0; j < 8; ++j)
            acc[m][j] = (f32x4){0.f, 0.f, 0.f, 0.f};

    const int swA = ((gA >> 1) & 3) << 4;
    const int swB = ((gB >> 1) & 3) << 4;
    const int kol = l >> 4;
    const float* aptr0 = nbp + (l & 15) * F0 + kol * 8;        // A row (m=0)
    const float* aptr1 = nbp + (16 + (l & 15)) * F0 + kol * 8; // A row (m=1)

    #pragma unroll 1
    for (int strip = 0; strip < 16; ++strip) {
        const int f0 = strip * 32;
        // prefetch GEMM1 A-frags (global fp32, L2-hot); consumed after barrier
        float4 a00 = *(const float4*)(aptr0 + f0);
        float4 a01 = *(const float4*)(aptr0 + f0 + 4);
        float4 a10 = *(const float4*)(aptr1 + f0);
        float4 a11 = *(const float4*)(aptr1 + f0 + 4);

        // ---- V construction: V[f0..f0+31][gA,gB] -> bf16 Vt ----
        #pragma unroll
        for (int ko = 0; ko < 4; ++ko) {
            float4 xf0 = ((const float4*)xl)[(f0 >> 2) + ko * 2];
            float4 xf1 = ((const float4*)xl)[(f0 >> 2) + ko * 2 + 1];
            float4 sf0 = ((const float4*)sl)[(f0 >> 2) + ko * 2];
            float4 sf1 = ((const float4*)sl)[(f0 >> 2) + ko * 2 + 1];
            const float xf[8] = {xf0.x, xf0.y, xf0.z, xf0.w, xf1.x, xf1.y, xf1.z, xf1.w};
            const float sf[8] = {sf0.x, sf0.y, sf0.z, sf0.w, sf1.x, sf1.y, sf1.z, sf1.w};
            unsigned pa[4], pb[4];
            float vpA = 0.f, vpB = 0.f;
            #pragma unroll
            for (int i = 0; i < 8; ++i) {
                float rA = xf[i] * sa + xa * sf[i];
                float aA = sqrtf(fabsf(rA));
                float vA = copysignf(aA, rA);
                float rB = xf[i] * sb + xb * sf[i];
                float aB = sqrtf(fabsf(rB));
                float vB = copysignf(aB, rB);
                if (i & 1) {
                    dA1 += aA; dB1 += aB; xA1 += xf[i] * vA; xB1 += xf[i] * vB;
                    pa[i >> 1] = cvt_pk_bf16(vpA, vA);
                    pb[i >> 1] = cvt_pk_bf16(vpB, vB);
                } else {
                    dA0 += aA; dB0 += aB; xA0 += xf[i] * vA; xB0 += xf[i] * vB;
                    vpA = vA; vpB = vB;
                }
            }
            uint4 ua; ua.x = pa[0]; ua.y = pa[1]; ua.z = pa[2]; ua.w = pa[3];
            uint4 ub; ub.x = pb[0]; ub.y = pb[1]; ub.z = pb[2]; ub.w = pb[3];
            *(uint4*)(smem + gA * 64 + ((ko * 16) ^ swA)) = ua;
            *(uint4*)(smem + gB * 64 + ((ko * 16) ^ swB)) = ub;
        }
        __syncthreads();

        // ---- MFMA: C[n][g] += A[n][f-strip] * Vt[g][f-strip]^T ----
        short8 afrag[2];
        {
            uint4 p0, p1;
            p0.x = cvt_pk_bf16(a00.x, a00.y); p0.y = cvt_pk_bf16(a00.z, a00.w);
            p0.z = cvt_pk_bf16(a01.x, a01.y); p0.w = cvt_pk_bf16(a01.z, a01.w);
            p1.x = cvt_pk_bf16(a10.x, a10.y); p1.y = cvt_pk_bf16(a10.z, a10.w);
            p1.z = cvt_pk_bf16(a11.x, a11.y); p1.w = cvt_pk_bf16(a11.z, a11.w);
            __builtin_memcpy(&afrag[0], &p0, 16);
            __builtin_memcpy(&afrag[1], &p1, 16);
        }
        #pragma unroll
        for (int j = 0; j < 8; ++j) {
            const int g = w * 128 + j * 16 + (l & 15);
            short8 bfrag = *(const short8*)(smem + g * 64 +
                            ((kol * 16) ^ (((g >> 1) & 3) << 4)));
            acc[0][j] = __builtin_amdgcn_mfma_f32_16x16x32_bf16(afrag[0], bfrag, acc[0][j], 0, 0, 0);
            acc[1][j] = __builtin_amdgcn_mfma_f32_16x16x32_bf16(afrag[1], bfrag, acc[1][j], 0, 0, 0);
        }
        __syncthreads();
    }

    // ---- norm factors: invD -> sl region, xgx -> xl region (both dead) ----
    {
        const float ia = 1.f / ((dA0 + dA1) + EPS_NORM);
        const float ib = 1.f / ((dB0 + dB1) + EPS_NORM);
        sl[gA] = ia; sl[gB] = ib;
        xl[gA] = (xA0 + xA1) * ia;
        xl[gB] = (xB0 + xB1) * ib;
    }
    __syncthreads();

    // ---- A' = bf16(acc * invD) into Vt region (dead after GEMM1) ----
    {
        float iv[8];
        #pragma unroll
        for (int j = 0; j < 8; ++j) iv[j] = sl[w * 128 + j * 16 + (l & 15)];
        #pragma unroll
        for (int m = 0; m < 2; ++m)
            #pragma unroll
            for (int j = 0; j < 8; ++j) {
                const int g = w * 128 + j * 16 + (l & 15);
                #pragma unroll
                for (int r = 0; r < 4; ++r) {
                    const int n = m * 16 + (l >> 4) * 4 + r;
                    *(unsigned short*)(smem + n * 1024 + ((2 * g) ^ ((n & 7) << 4))) =
                        (unsigned short)cvt_pk_bf16(acc[m][j][r] * iv[j], 0.f);
                }
            }
    }
    __syncthreads();

    // ---- phase 3 MFMA: nbh[n][de] += A'[n][g]*w1t[de][g]; h[de] via sparse A ----
    f32x4 acc3[2];
    acc3[0] = (f32x4){0.f, 0.f, 0.f, 0.f};
    acc3[1] = (f32x4){0.f, 0.f, 0.f, 0.f};
    f32x4 acch = (f32x4){0.f, 0.f, 0.f, 0.f};
    {
        const int de = w * 16 + (l & 15);
        const unsigned short* wtp = w1t + ((size_t)(k * 64 + de) * 512) + kol * 8;
        const float* xgx = xl;
        #pragma unroll 2
        for (int ks = 0; ks < 16; ++ks) {
            short8 bfrag = *(const short8*)(wtp + ks * 32);
            short8 afh = {0, 0, 0, 0, 0, 0, 0, 0};
            if ((l & 15) == 0) {
                float4 p0 = *(const float4*)(xgx + ks * 32 + kol * 8);
                float4 p1 = *(const float4*)(xgx + ks * 32 + kol * 8 + 4);
                uint4 pk;
                pk.x = cvt_pk_bf16(p0.x, p0.y); pk.y = cvt_pk_bf16(p0.z, p0.w);
                pk.z = cvt_pk_bf16(p1.x, p1.y); pk.w = cvt_pk_bf16(p1.z, p1.w);
                __builtin_memcpy(&afh, &pk, 16);
            }
            #pragma unroll
            for (int m = 0; m < 2; ++m) {
                const int n = m * 16 + (l & 15);
                short8 af = *(const short8*)(smem + n * 1024 +
                            ((ks * 64 + kol * 16) ^ ((n & 7) << 4)));
                acc3[m] = __builtin_amdgcn_mfma_f32_16x16x32_bf16(af, bfrag, acc3[m], 0, 0, 0);
            }
            acch = __builtin_amdgcn_mfma_f32_16x16x32_bf16(afh, bfrag, acch, 0, 0, 0);
        }
    }

    // ---- nbh BN (per d=w over 512 (n,e)) + softsign + sum over n ----
    {
        float vals[8];
        float s1 = 0.f, s2 = 0.f;
        #pragma unroll
        for (int m = 0; m < 2; ++m)
            #pragma unroll
            for (int r = 0; r < 4; ++r) {
                float v = acc3[m][r];
                vals[m * 4 + r] = v; s1 += v; s2 += v * v;
            }
        #pragma unroll
        for (int off = 32; off >= 1; off >>= 1) {
            s1 += __shfl_xor(s1, off);
            s2 += __shfl_xor(s2, off);
        }
        const float mean = s1 * (1.f / 512.f);
        const float var  = s2 * (1.f / 512.f) - mean * mean;
        const float An   = g1[k * C1 + w] * rsqrtf(var + EPS_BN);
        const float Bn   = b1[k * C1 + w] - mean * An;
        float nbse = 0.f;
        #pragma unroll
        for (int i = 0; i < 8; ++i) nbse += softsignf(vals[i] * An + Bn);
        nbse += __shfl_xor(nbse, 16);
        nbse += __shfl_xor(nbse, 32);
        if (l < 16) nbs_out[pair * 64 + w * 16 + l] = nbse;
    }

    // ---- h output + global BN-h partial stats (d = w, e = l) ----
    if (l < 16) {
        float hv = acch[0];
        h_raw[pair * 64 + w * 16 + l] = hv;
        float s1 = hv, s2 = hv * hv;
        #pragma unroll
        for (int off = 1; off <= 8; off <<= 1) {
            s1 += __shfl_xor(s1, off);
            s2 += __shfl_xor(s2, off);
        }
        if (l == 0) {
            atomicAdd(&hsum[k * 4 + w], s1);
            atomicAdd(&hsum[8 + k * 4 + w], s2);
        }
    }
}

// ---------------------------------------------------------------------------
// Kernel 2: per (b,k) wave: softsign(bn(h)) via hsum, fadj2 (16x16), xg2,
// W2 -> h2_raw; accumulates global h2 BN stats into h2sum via atomics.
// ---------------------------------------------------------------------------
__global__ __launch_bounds__(256) void k_stage2(
    const float* __restrict__ h_rawg, const float* __restrict__ nbsg,
    const float* __restrict__ hsum,
    const float* __restrict__ g1, const float* __restrict__ b1,
    const float* __restrict__ W2,
    float* __restrict__ h2_raw, float* __restrict__ h2sum)
{
    __shared__ float hl[4][64], nl[4][64], fl[4][256], xg2l[4][64];
    const int t = threadIdx.x, wv = t >> 6, l = t & 63;
    const int pair = blockIdx.x * 4 + wv;
    const int k = pair & 1;
    const int d = l >> 4;
    {
        const float S1 = hsum[k * 4 + d], S2 = hsum[8 + k * 4 + d];
        const float mean = S1 * (1.f / 8192.f);
        const float var  = S2 * (1.f / 8192.f) - mean * mean;
        const float A = g1[k * 4 + d] * rsqrtf(var + EPS_BN);
        const float Bc = b1[k * 4 + d] - mean * A;
        float hv = h_rawg[pair * 64 + l];
        hl[wv][l] = softsignf(hv * A + Bc);
        nl[wv][l] = nbsg[pair * 64 + l];
    }
    __syncthreads();
    const int gcol = l & 15;
    float raw[4];
    #pragma unroll
    for (int j = 0; j < 4; ++j) {
        const int idx = l + 64 * j;       // idx = f*16+g (g == gcol)
        const int f = idx >> 4;
        float a = 0.f;
        #pragma unroll
        for (int c = 0; c < 4; ++c) a += hl[wv][c * 16 + f] * nl[wv][c * 16 + gcol];
        raw[j] = a;
        fl[wv][idx] = a;
    }
    __syncthreads();
    float w4[4]; float Dp = 0.f;
    #pragma unroll
    for (int j = 0; j < 4; ++j) {
        const int idx = l + 64 * j;
        const int f = idx >> 4;
        float v = raw[j] + fl[wv][gcol * 16 + f];   // symmetrize
        float a = sqrtf(fabsf(v));
        Dp += a;
        w4[j] = copysignf(a, v);
    }
    Dp += __shfl_xor(Dp, 16);
    Dp += __shfl_xor(Dp, 32);
    const float invD = 1.f / (Dp + EPS_NORM);
    __syncthreads();
    #pragma unroll
    for (int j = 0; j < 4; ++j) fl[wv][l + 64 * j] = w4[j] * invD;
    __syncthreads();
    {
        const int c = l >> 4;
        float a = 0.f;
        #pragma unroll
        for (int f = 0; f < 16; ++f) a += hl[wv][c * 16 + f] * fl[wv][f * 16 + gcol];
        xg2l[wv][c * 16 + gcol] = a;
    }
    __syncthreads();
    if (l < 32) {
        const float* W2p = W2 + k * (C2 * C1 * F1) + l * (C1 * F1);
        float a = 0.f;
        #pragma unroll
        for (int i = 0; i < 64; ++i) a += xg2l[wv][i] * W2p[i];
        h2_raw[pair * 32 + l] = a;
        atomicAdd(&h2sum[k * 32 + l], a);
        atomicAdd(&h2sum[64 + k * 32 + l], a * a);
    }
}

// ---------------------------------------------------------------------------
// Kernel 3: per-b classifier: softsign(bn(h2)) via h2sum -> relu(64x32) -> 32x40
// ---------------------------------------------------------------------------
__global__ __launch_bounds__(64) void k_cls(
    const float* __restrict__ h2_raw, const float* __restrict__ h2sum,
    const float* __restrict__ g2, const float* __restrict__ b2,
    const float* __restrict__ Wc1, const float* __restrict__ bc1,
    const float* __restrict__ Wc2, const float* __restrict__ bc2,
    float* __restrict__ out)
{
    __shared__ float flat[64];
    __shared__ float hid[32];
    const int b = blockIdx.x, l = threadIdx.x;
    const int k = l >> 5, d = l & 31;     // flat index = k*32+d = l
    {
        const float S1 = h2sum[l], S2 = h2sum[64 + l];
        const float mean = S1 * (1.f / 512.f);
        const float var  = S2 * (1.f / 512.f) - mean * mean;
        const float A = g2[l] * rsqrtf(var + EPS_BN);
        const float Bc = b2[l] - mean * A;
        float v = h2_raw[(b * 2 + k) * 32 + d];
        flat[l] = softsignf(v * A + Bc);
    }
    __syncthreads();
    if (l < 32) {
        float a = bc1[l];
        #pragma unroll
        for (int i = 0; i < 64; ++i) a += flat[i] * Wc1[i * 32 + l];
        hid[l] = fmaxf(a, 0.f);
    }
    __syncthreads();
    if (l < NCLS) {
        float a = bc2[l];
        #pragma unroll
        for (int j = 0; j < 32; ++j) a += hid[j] * Wc2[j * NCLS + l];
        out[b * NCLS + l] = a;
    }
}

// ---------------------------------------------------------------------------
extern "C" void kernel_launch(void* const* d_in, const int* in_sizes, int n_in,
                              void* d_out, int out_size, void* d_ws, size_t ws_size,
                              hipStream_t stream)
{
    const float* x   = (const float*)d_in[0];
    const float* nbg = (const float*)d_in[1];
    const float* W1  = (const float*)d_in[2];
    const float* g1  = (const float*)d_in[3];
    const float* b1  = (const float*)d_in[4];
    const float* W2  = (const float*)d_in[5];
    const float* g2  = (const float*)d_in[6];
    const float* b2  = (const float*)d_in[7];
    const float* Wc1 = (const float*)d_in[8];
    const float* bc1 = (const float*)d_in[9];
    const float* Wc2 = (const float*)d_in[10];
    const float* bc2 = (const float*)d_in[11];
    float* out = (float*)d_out;
    float* ws  = (float*)d_ws;

    // workspace layout (floats):
    float* h_raw  = ws;                   // B*K*64 = 65536
    float* nbs    = ws + 65536;           // B*K*64 = 65536
    float* h2_raw = ws + 131072;          // B*K*32 = 32768 (131072 B)
    float* stats  = ws + 163840;          // hsum[16] + h2sum[128]
    float* hsum   = stats;
    float* h2sum  = stats + 16;
    // w1t (bf16, 2*64*512 ushorts = 131072 B) aliases h2_raw: consumed by
    // k_main before k_stage2 writes h2_raw (stream-ordered).
    unsigned short* w1t = (unsigned short*)h2_raw;

    hipMemsetAsync(stats, 0, 144 * sizeof(float), stream);
    hipLaunchKernelGGL(k_prep,   dim3(256),             dim3(256), 0, stream, W1, w1t);
    hipLaunchKernelGGL(k_main,   dim3(B_SZ * KHOP),     dim3(256), SMEM_MAIN, stream,
                       x, nbg, w1t, g1, b1, h_raw, nbs, hsum);
    hipLaunchKernelGGL(k_stage2, dim3(B_SZ * KHOP / 4), dim3(256), 0, stream,
                       h_raw, nbs, hsum, g1, b1, W2, h2_raw, h2sum);
    hipLaunchKernelGGL(k_cls,    dim3(B_SZ),            dim3(64), 0, stream,
                       h2_raw, h2sum, g2, b2, Wc1, bc1, Wc2, bc2, out);
}

// Round 5
// 321.769 us; speedup vs baseline: 1.0259x; 1.0259x over previous
//
#include <hip/hip_runtime.h>
#include <hip/hip_bf16.h>

#define B_SZ 512
#define KHOP 2
#define NNB  32
#define F0   512
#define C1   4
#define F1   16
#define C2   32
#define NCLS 40

#define EPS_BN   1e-5f
#define EPS_NORM 1e-7f

typedef __attribute__((ext_vector_type(8))) short short8;
typedef __attribute__((ext_vector_type(4))) float f32x4;

__device__ __forceinline__ float softsignf(float v) { return v / (1.0f + fabsf(v)); }

// HW packed f32->bf16 (RNE). lo -> bits[15:0], hi -> bits[31:16].
__device__ __forceinline__ unsigned cvt_pk_bf16(float lo, float hi) {
    unsigned r;
    asm("v_cvt_pk_bf16_f32 %0, %1, %2" : "=v"(r) : "v"(lo), "v"(hi));
    return r;
}

// ---------------------------------------------------------------------------
// Prep: W1 (K,C1,1,F0,F1) fp32 -> w1t bf16 [k][de=d*16+e][g]  (contiguous
// 16B B-frags for phase-3 MFMA, served from L2).
// ---------------------------------------------------------------------------
__global__ __launch_bounds__(256) void k_prep(const float* __restrict__ W1,
                                              unsigned short* __restrict__ w1t)
{
    const int idx = blockIdx.x * 256 + threadIdx.x;   // [0, 65536)
    const int g  = idx & 511;
    const int de = (idx >> 9) & 63;
    const int kk = idx >> 15;
    const int d = de >> 4, e = de & 15;
    w1t[idx] = (unsigned short)cvt_pk_bf16(W1[((size_t)((kk * 4 + d) * 512) + g) * 16 + e], 0.f);
}

// ---------------------------------------------------------------------------
// Kernel 1: per (b,k) block, 512 threads (8 waves), one V-column per thread.
// LDS (69632 B = 68 KiB -> 2 blocks/CU = 16 waves/CU):
//   [0,32768)      A: nb bf16 [32 n][512 f], byte = n*1024 + (2f ^ ((n&7)<<4))
//                  -> after GEMM1 overwritten by A' = xg bf16 [32 n][512 g]
//   [32768,65536)  Vt strip bf16 [512 g][32 f], byte = g*64 + (2f' ^ (((g>>1)&3)<<4))
//                  transient uses: s-partials fp32[8][512] (phase 0);
//                  invD fp32[512] @32768, xgx fp32[512] @34816 (post-GEMM1);
//                  redst[16] @32768, pnb[128] @32832 (BN tail)
//   [65536,67584)  xl fp32[512]
//   [67584,69632)  sl fp32[512]
// ---------------------------------------------------------------------------
#define SMEM_MAIN 69632

__global__ __launch_bounds__(512, 4) void k_main(
    const float* __restrict__ xg_, const float* __restrict__ nbg,
    const unsigned short* __restrict__ w1t,
    const float* __restrict__ g1, const float* __restrict__ b1,
    float* __restrict__ h_raw, float* __restrict__ nbs_out,
    float* __restrict__ hsum)
{
    extern __shared__ char smem[];
    float* xl = (float*)(smem + 65536);
    float* sl = (float*)(smem + 67584);

    const int t = threadIdx.x;
    const int pair = blockIdx.x;          // b*2 + k
    const int b = pair >> 1, k = pair & 1;
    const int l = t & 63, w = t >> 6;     // 8 waves
    const int m = w & 1, gsb = w >> 1;    // wave -> (n-halftile, g-superblock)
    const int kol = l >> 4;
    const float* nbp = nbg + (size_t)pair * (NNB * F0);

    // ---- phase 0: stage nb -> bf16 A (swizzled) + s-partials; load x ----
    {
        const int oct = t & 63, ng = t >> 6;   // 64 f-octets x 8 n-groups
        const int f0s = oct * 8;
        float sp0=0,sp1=0,sp2=0,sp3=0,sp4=0,sp5=0,sp6=0,sp7=0;
        #pragma unroll
        for (int ni = 0; ni < 4; ++ni) {
            const int n = ng * 4 + ni;
            float4 q0 = *(const float4*)(nbp + n * F0 + f0s);
            float4 q1 = *(const float4*)(nbp + n * F0 + f0s + 4);
            sp0 += q0.x; sp1 += q0.y; sp2 += q0.z; sp3 += q0.w;
            sp4 += q1.x; sp5 += q1.y; sp6 += q1.z; sp7 += q1.w;
            uint4 p;
            p.x = cvt_pk_bf16(q0.x, q0.y);
            p.y = cvt_pk_bf16(q0.z, q0.w);
            p.z = cvt_pk_bf16(q1.x, q1.y);
            p.w = cvt_pk_bf16(q1.z, q1.w);
            *(uint4*)(smem + n * 1024 + ((2 * f0s) ^ ((n & 7) << 4))) = p;
        }
        float* part = (float*)(smem + 32768);   // [8 ng][512 f]
        *(float4*)(part + ng * 512 + f0s)     = make_float4(sp0, sp1, sp2, sp3);
        *(float4*)(part + ng * 512 + f0s + 4) = make_float4(sp4, sp5, sp6, sp7);
        xl[t] = xg_[b * F0 + t];
    }
    __syncthreads();
    {
        const float* part = (const float*)(smem + 32768);
        float s = 0.f;
        #pragma unroll
        for (int p = 0; p < 8; ++p) s += part[p * 512 + t];
        sl[t] = s;
    }
    __syncthreads();

    // ---- GEMM1 with fused V construction (one column g = t per thread) ----
    const float xv = xl[t], sv = sl[t];
    float dS0 = 0.f, dS1 = 0.f, xS0 = 0.f, xS1 = 0.f;
    f32x4 acc[8];
    #pragma unroll
    for (int j = 0; j < 8; ++j) acc[j] = (f32x4){0.f, 0.f, 0.f, 0.f};

    const int swz = ((t >> 1) & 3) << 4;
    const int nA  = m * 16 + (l & 15);
    const int aSw = (nA & 7) << 4;

    #pragma unroll 1
    for (int strip = 0; strip < 16; ++strip) {
        const int f0 = strip * 32;
        #pragma unroll
        for (int ko = 0; ko < 4; ++ko) {
            float4 xf0 = ((const float4*)xl)[(f0 >> 2) + ko * 2];
            float4 xf1 = ((const float4*)xl)[(f0 >> 2) + ko * 2 + 1];
            float4 sf0 = ((const float4*)sl)[(f0 >> 2) + ko * 2];
            float4 sf1 = ((const float4*)sl)[(f0 >> 2) + ko * 2 + 1];
            const float xf[8] = {xf0.x, xf0.y, xf0.z, xf0.w, xf1.x, xf1.y, xf1.z, xf1.w};
            const float sf[8] = {sf0.x, sf0.y, sf0.z, sf0.w, sf1.x, sf1.y, sf1.z, sf1.w};
            unsigned pk[4];
            float vprev = 0.f;
            #pragma unroll
            for (int i = 0; i < 8; ++i) {
                float r = sf[i] * xv + xf[i] * sv;
                float a = sqrtf(fabsf(r));
                float v = copysignf(a, r);
                if (i & 1) {
                    dS1 += a; xS1 += xf[i] * v;
                    pk[i >> 1] = cvt_pk_bf16(vprev, v);
                } else {
                    dS0 += a; xS0 += xf[i] * v;
                    vprev = v;
                }
            }
            uint4 u; u.x = pk[0]; u.y = pk[1]; u.z = pk[2]; u.w = pk[3];
            *(uint4*)(smem + 32768 + t * 64 + ((ko * 16) ^ swz)) = u;
        }
        __syncthreads();
        // MFMA: wave (m, gsb) -> C[n in m-half][g in gsb*128..+128]
        short8 afrag = *(const short8*)(smem + nA * 1024 +
                        ((f0 * 2 + kol * 16) ^ aSw));
        #pragma unroll
        for (int j = 0; j < 8; ++j) {
            const int g = gsb * 128 + j * 16 + (l & 15);
            short8 bfrag = *(const short8*)(smem + 32768 + g * 64 +
                            ((kol * 16) ^ (((g >> 1) & 3) << 4)));
            acc[j] = __builtin_amdgcn_mfma_f32_16x16x32_bf16(afrag, bfrag, acc[j], 0, 0, 0);
        }
        __syncthreads();
    }

    // ---- norm factors into Vt region (dead) ----
    {
        const float ia = 1.f / ((dS0 + dS1) + EPS_NORM);
        ((float*)(smem + 32768))[t] = ia;                 // invD
        ((float*)(smem + 34816))[t] = (xS0 + xS1) * ia;   // xgx
    }
    __syncthreads();

    // ---- A' = bf16(acc * invD), overwriting A region ----
    {
        const float* invD = (const float*)(smem + 32768);
        #pragma unroll
        for (int j = 0; j < 8; ++j) {
            const int g = gsb * 128 + j * 16 + (l & 15);
            const float iv = invD[g];
            #pragma unroll
            for (int r = 0; r < 4; ++r) {
                const int n = m * 16 + (l >> 4) * 4 + r;
                *(unsigned short*)(smem + n * 1024 + ((2 * g) ^ ((n & 7) << 4))) =
                    (unsigned short)cvt_pk_bf16(acc[j][r] * iv, 0.f);
            }
        }
    }
    __syncthreads();

    // ---- phase 3 MFMA: nbh[n][de] = A'[n][g] * w1t[de][g]; h via sparse x-row ----
    f32x4 acc3 = (f32x4){0.f, 0.f, 0.f, 0.f};
    f32x4 acch = (f32x4){0.f, 0.f, 0.f, 0.f};
    {
        const int de = gsb * 16 + (l & 15);
        const unsigned short* wtp = w1t + ((size_t)(k * 64 + de) * 512) + kol * 8;
        const float* xgx = (const float*)(smem + 34816);
        #pragma unroll 2
        for (int ks = 0; ks < 16; ++ks) {
            short8 bfrag = *(const short8*)(wtp + ks * 32);
            short8 af = *(const short8*)(smem + nA * 1024 +
                        ((ks * 64 + kol * 16) ^ aSw));
            acc3 = __builtin_amdgcn_mfma_f32_16x16x32_bf16(af, bfrag, acc3, 0, 0, 0);
            if (m == 0) {
                short8 afh = {0, 0, 0, 0, 0, 0, 0, 0};
                if ((l & 15) == 0) {
                    float4 p0 = *(const float4*)(xgx + ks * 32 + kol * 8);
                    float4 p1 = *(const float4*)(xgx + ks * 32 + kol * 8 + 4);
                    uint4 pk;
                    pk.x = cvt_pk_bf16(p0.x, p0.y); pk.y = cvt_pk_bf16(p0.z, p0.w);
                    pk.z = cvt_pk_bf16(p1.x, p1.y); pk.w = cvt_pk_bf16(p1.z, p1.w);
                    __builtin_memcpy(&afh, &pk, 16);
                }
                acch = __builtin_amdgcn_mfma_f32_16x16x32_bf16(afh, bfrag, acch, 0, 0, 0);
            }
        }
    }

    // ---- nbh BN per d=gsb over (n,e): cross-wave-pair reduction ----
    float* redst = (float*)(smem + 32768);        // [8 waves][2]
    float* pnb   = (float*)(smem + 32832);        // [2 m][4 d][16 e]
    {
        float vals[4];
        float s1 = 0.f, s2 = 0.f;
        #pragma unroll
        for (int r = 0; r < 4; ++r) {
            float v = acc3[r];
            vals[r] = v; s1 += v; s2 += v * v;
        }
        #pragma unroll
        for (int off = 32; off >= 1; off >>= 1) {
            s1 += __shfl_xor(s1, off);
            s2 += __shfl_xor(s2, off);
        }
        if (l == 0) { redst[w * 2] = s1; redst[w * 2 + 1] = s2; }
        __syncthreads();
        const float S1 = redst[w * 2]     + redst[(w ^ 1) * 2];
        const float S2 = redst[w * 2 + 1] + redst[(w ^ 1) * 2 + 1];
        const float mean = S1 * (1.f / 512.f);
        const float var  = S2 * (1.f / 512.f) - mean * mean;
        const float An   = g1[k * C1 + gsb] * rsqrtf(var + EPS_BN);
        const float Bn   = b1[k * C1 + gsb] - mean * An;
        float nbse = 0.f;
        #pragma unroll
        for (int r = 0; r < 4; ++r) nbse += softsignf(vals[r] * An + Bn);
        nbse += __shfl_xor(nbse, 16);   // reduce over n-groups (l>>4)
        nbse += __shfl_xor(nbse, 32);
        if (l < 16) pnb[m * 64 + gsb * 16 + l] = nbse;

        if (m == 0 && l < 16) {         // h output: x-row of acch (n=0 -> lanes 0..15, reg 0)
            float hv = acch[0];
            h_raw[pair * 64 + gsb * 16 + l] = hv;
            float t1 = hv, t2 = hv * hv;
            #pragma unroll
            for (int off = 1; off <= 8; off <<= 1) {
                t1 += __shfl_xor(t1, off);
                t2 += __shfl_xor(t2, off);
            }
            if (l == 0) {
                atomicAdd(&hsum[k * 4 + gsb], t1);
                atomicAdd(&hsum[8 + k * 4 + gsb], t2);
            }
        }
    }
    __syncthreads();
    if (t < 64) nbs_out[pair * 64 + t] = pnb[t] + pnb[64 + t];
}

// ---------------------------------------------------------------------------
// Kernel 2: per (b,k) wave: softsign(bn(h)) via hsum, fadj2 (16x16), xg2,
// W2 -> h2_raw; accumulates global h2 BN stats into h2sum via atomics.
// ---------------------------------------------------------------------------
__global__ __launch_bounds__(256) void k_stage2(
    const float* __restrict__ h_rawg, const float* __restrict__ nbsg,
    const float* __restrict__ hsum,
    const float* __restrict__ g1, const float* __restrict__ b1,
    const float* __restrict__ W2,
    float* __restrict__ h2_raw, float* __restrict__ h2sum)
{
    __shared__ float hl[4][64], nl[4][64], fl[4][256], xg2l[4][64];
    const int t = threadIdx.x, wv = t >> 6, l = t & 63;
    const int pair = blockIdx.x * 4 + wv;
    const int k = pair & 1;
    const int d = l >> 4;
    {
        const float S1 = hsum[k * 4 + d], S2 = hsum[8 + k * 4 + d];
        const float mean = S1 * (1.f / 8192.f);
        const float var  = S2 * (1.f / 8192.f) - mean * mean;
        const float A = g1[k * 4 + d] * rsqrtf(var + EPS_BN);
        const float Bc = b1[k * 4 + d] - mean * A;
        float hv = h_rawg[pair * 64 + l];
        hl[wv][l] = softsignf(hv * A + Bc);
        nl[wv][l] = nbsg[pair * 64 + l];
    }
    __syncthreads();
    const int gcol = l & 15;
    float raw[4];
    #pragma unroll
    for (int j = 0; j < 4; ++j) {
        const int idx = l + 64 * j;       // idx = f*16+g (g == gcol)
        const int f = idx >> 4;
        float a = 0.f;
        #pragma unroll
        for (int c = 0; c < 4; ++c) a += hl[wv][c * 16 + f] * nl[wv][c * 16 + gcol];
        raw[j] = a;
        fl[wv][idx] = a;
    }
    __syncthreads();
    float w4[4]; float Dp = 0.f;
    #pragma unroll
    for (int j = 0; j < 4; ++j) {
        const int idx = l + 64 * j;
        const int f = idx >> 4;
        float v = raw[j] + fl[wv][gcol * 16 + f];   // symmetrize
        float a = sqrtf(fabsf(v));
        Dp += a;
        w4[j] = copysignf(a, v);
    }
    Dp += __shfl_xor(Dp, 16);
    Dp += __shfl_xor(Dp, 32);
    const float invD = 1.f / (Dp + EPS_NORM);
    __syncthreads();
    #pragma unroll
    for (int j = 0; j < 4; ++j) fl[wv][l + 64 * j] = w4[j] * invD;
    __syncthreads();
    {
        const int c = l >> 4;
        float a = 0.f;
        #pragma unroll
        for (int f = 0; f < 16; ++f) a += hl[wv][c * 16 + f] * fl[wv][f * 16 + gcol];
        xg2l[wv][c * 16 + gcol] = a;
    }
    __syncthreads();
    if (l < 32) {
        const float* W2p = W2 + k * (C2 * C1 * F1) + l * (C1 * F1);
        float a = 0.f;
        #pragma unroll
        for (int i = 0; i < 64; ++i) a += xg2l[wv][i] * W2p[i];
        h2_raw[pair * 32 + l] = a;
        atomicAdd(&h2sum[k * 32 + l], a);
        atomicAdd(&h2sum[64 + k * 32 + l], a * a);
    }
}

// ---------------------------------------------------------------------------
// Kernel 3: per-b classifier: softsign(bn(h2)) via h2sum -> relu(64x32) -> 32x40
// ---------------------------------------------------------------------------
__global__ __launch_bounds__(64) void k_cls(
    const float* __restrict__ h2_raw, const float* __restrict__ h2sum,
    const float* __restrict__ g2, const float* __restrict__ b2,
    const float* __restrict__ Wc1, const float* __restrict__ bc1,
    const float* __restrict__ Wc2, const float* __restrict__ bc2,
    float* __restrict__ out)
{
    __shared__ float flat[64];
    __shared__ float hid[32];
    const int b = blockIdx.x, l = threadIdx.x;
    const int k = l >> 5, d = l & 31;     // flat index = k*32+d = l
    {
        const float S1 = h2sum[l], S2 = h2sum[64 + l];
        const float mean = S1 * (1.f / 512.f);
        const float var  = S2 * (1.f / 512.f) - mean * mean;
        const float A = g2[l] * rsqrtf(var + EPS_BN);
        const float Bc = b2[l] - mean * A;
        float v = h2_raw[(b * 2 + k) * 32 + d];
        flat[l] = softsignf(v * A + Bc);
    }
    __syncthreads();
    if (l < 32) {
        float a = bc1[l];
        #pragma unroll
        for (int i = 0; i < 64; ++i) a += flat[i] * Wc1[i * 32 + l];
        hid[l] = fmaxf(a, 0.f);
    }
    __syncthreads();
    if (l < NCLS) {
        float a = bc2[l];
        #pragma unroll
        for (int j = 0; j < 32; ++j) a += hid[j] * Wc2[j * NCLS + l];
        out[b * NCLS + l] = a;
    }
}

// ---------------------------------------------------------------------------
extern "C" void kernel_launch(void* const* d_in, const int* in_sizes, int n_in,
                              void* d_out, int out_size, void* d_ws, size_t ws_size,
                              hipStream_t stream)
{
    const float* x   = (const float*)d_in[0];
    const float* nbg = (const float*)d_in[1];
    const float* W1  = (const float*)d_in[2];
    const float* g1  = (const float*)d_in[3];
    const float* b1  = (const float*)d_in[4];
    const float* W2  = (const float*)d_in[5];
    const float* g2  = (const float*)d_in[6];
    const float* b2  = (const float*)d_in[7];
    const float* Wc1 = (const float*)d_in[8];
    const float* bc1 = (const float*)d_in[9];
    const float* Wc2 = (const float*)d_in[10];
    const float* bc2 = (const float*)d_in[11];
    float* out = (float*)d_out;
    float* ws  = (float*)d_ws;

    // workspace layout (floats):
    float* h_raw  = ws;                   // B*K*64 = 65536
    float* nbs    = ws + 65536;           // B*K*64 = 65536
    float* h2_raw = ws + 131072;          // B*K*32 = 32768 (131072 B)
    float* stats  = ws + 163840;          // hsum[16] + h2sum[128]
    float* hsum   = stats;
    float* h2sum  = stats + 16;
    // w1t (bf16, 2*64*512 ushorts = 131072 B) aliases h2_raw: consumed by
    // k_main before k_stage2 writes h2_raw (stream-ordered).
    unsigned short* w1t = (unsigned short*)h2_raw;

    hipMemsetAsync(stats, 0, 144 * sizeof(float), stream);
    hipLaunchKernelGGL(k_prep,   dim3(256),             dim3(256), 0, stream, W1, w1t);
    hipLaunchKernelGGL(k_main,   dim3(B_SZ * KHOP),     dim3(512), SMEM_MAIN, stream,
                       x, nbg, w1t, g1, b1, h_raw, nbs, hsum);
    hipLaunchKernelGGL(k_stage2, dim3(B_SZ * KHOP / 4), dim3(256), 0, stream,
                       h_raw, nbs, hsum, g1, b1, W2, h2_raw, h2sum);
    hipLaunchKernelGGL(k_cls,    dim3(B_SZ),            dim3(64), 0, stream,
                       h2_raw, h2sum, g2, b2, Wc1, bc1, Wc2, bc2, out);
}

// Round 6
// 301.757 us; speedup vs baseline: 1.0940x; 1.0663x over previous
//
#include <hip/hip_runtime.h>
#include <hip/hip_bf16.h>

#define B_SZ 512
#define KHOP 2
#define NNB  32
#define F0   512
#define C1   4
#define F1   16
#define C2   32
#define NCLS 40

#define EPS_BN   1e-5f
#define EPS_NORM 1e-7f

typedef __attribute__((ext_vector_type(8))) short short8;
typedef __attribute__((ext_vector_type(4))) float f32x4;

__device__ __forceinline__ float softsignf(float v) { return v / (1.0f + fabsf(v)); }

// HW packed f32->bf16 (RNE). lo -> bits[15:0], hi -> bits[31:16].
__device__ __forceinline__ unsigned cvt_pk_bf16(float lo, float hi) {
    unsigned r;
    asm("v_cvt_pk_bf16_f32 %0, %1, %2" : "=v"(r) : "v"(lo), "v"(hi));
    return r;
}

// Single-instruction sqrt (input >= 0 here; ~1 ulp, fine for our threshold).
__device__ __forceinline__ float vsqrtf(float x) {
    float r;
    asm("v_sqrt_f32 %0, %1" : "=v"(r) : "v"(x));
    return r;
}

// ---------------------------------------------------------------------------
// Prep: W1 (K,C1,1,F0,F1) fp32 -> w1t bf16 [k][de=d*16+e][g]; also zeroes the
// stats accumulators (hsum/h2sum) so no separate memset launch is needed.
// ---------------------------------------------------------------------------
__global__ __launch_bounds__(256) void k_prep(const float* __restrict__ W1,
                                              unsigned short* __restrict__ w1t,
                                              float* __restrict__ stats)
{
    const int idx = blockIdx.x * 256 + threadIdx.x;   // [0, 65536)
    if (blockIdx.x == 0 && threadIdx.x < 144) stats[threadIdx.x] = 0.f;
    const int g  = idx & 511;
    const int de = (idx >> 9) & 63;
    const int kk = idx >> 15;
    const int d = de >> 4, e = de & 15;
    w1t[idx] = (unsigned short)cvt_pk_bf16(W1[((size_t)((kk * 4 + d) * 512) + g) * 16 + e], 0.f);
}

// ---------------------------------------------------------------------------
// Kernel 1: per (b,k) block, 512 threads (8 waves), one V-column per thread.
// LDS (102400 B = 100 KiB -> 1 block/CU = 8 waves/CU):
//   [0,32768)        A: nb bf16 [32 n][512 f], byte = n*1024 + (2f ^ ((n&7)<<4))
//                    -> after GEMM1 overwritten by A' = xg bf16 [32 n][512 g]
//   [32768,98304)    Vt double buffer: buf p @ 32768 + p*32768,
//                    layout g*64 + (2f' ^ (((g>>1)&3)<<4))
//                    transient: s-partials fp32[8][512] @32768 (phase 0);
//                    invD fp32[512] @32768, xgx fp32[512] @34816 (post-GEMM1);
//                    redst @36864, pnb @36928 (BN tail)
//   [98304,100352)   xl fp32[512]
//   [100352,102400)  sl fp32[512]
// One barrier per strip: V-compute of strip s+1 writes the buffer last read
// by MFMA of strip s-1; every wave is provably past that read (barrier s
// drains lgkmcnt), so the single barrier suffices.
// ---------------------------------------------------------------------------
#define VT_BASE 32768
#define SMEM_MAIN 102400

__global__ __launch_bounds__(512, 2) void k_main(
    const float* __restrict__ xg_, const float* __restrict__ nbg,
    const unsigned short* __restrict__ w1t,
    const float* __restrict__ g1, const float* __restrict__ b1,
    float* __restrict__ h_raw, float* __restrict__ nbs_out,
    float* __restrict__ hsum)
{
    extern __shared__ char smem[];
    float* xl = (float*)(smem + 98304);
    float* sl = (float*)(smem + 100352);

    const int t = threadIdx.x;
    const int pair = blockIdx.x;          // b*2 + k
    const int b = pair >> 1, k = pair & 1;
    const int l = t & 63, w = t >> 6;     // 8 waves
    const int m = w & 1, gsb = w >> 1;    // wave -> (n-halftile, g-superblock)
    const int kol = l >> 4;
    const float* nbp = nbg + (size_t)pair * (NNB * F0);

    // ---- phase 0: stage nb -> bf16 A (swizzled) + s-partials; load x ----
    {
        const int oct = t & 63, ng = t >> 6;   // 64 f-octets x 8 n-groups
        const int f0s = oct * 8;
        float sp0=0,sp1=0,sp2=0,sp3=0,sp4=0,sp5=0,sp6=0,sp7=0;
        #pragma unroll
        for (int ni = 0; ni < 4; ++ni) {
            const int n = ng * 4 + ni;
            float4 q0 = *(const float4*)(nbp + n * F0 + f0s);
            float4 q1 = *(const float4*)(nbp + n * F0 + f0s + 4);
            sp0 += q0.x; sp1 += q0.y; sp2 += q0.z; sp3 += q0.w;
            sp4 += q1.x; sp5 += q1.y; sp6 += q1.z; sp7 += q1.w;
            uint4 p;
            p.x = cvt_pk_bf16(q0.x, q0.y);
            p.y = cvt_pk_bf16(q0.z, q0.w);
            p.z = cvt_pk_bf16(q1.x, q1.y);
            p.w = cvt_pk_bf16(q1.z, q1.w);
            *(uint4*)(smem + n * 1024 + ((2 * f0s) ^ ((n & 7) << 4))) = p;
        }
        float* part = (float*)(smem + VT_BASE);   // [8 ng][512 f]
        *(float4*)(part + ng * 512 + f0s)     = make_float4(sp0, sp1, sp2, sp3);
        *(float4*)(part + ng * 512 + f0s + 4) = make_float4(sp4, sp5, sp6, sp7);
        xl[t] = xg_[b * F0 + t];
    }
    __syncthreads();
    {
        const float* part = (const float*)(smem + VT_BASE);
        float s = 0.f;
        #pragma unroll
        for (int p = 0; p < 8; ++p) s += part[p * 512 + t];
        sl[t] = s;
    }
    __syncthreads();

    // ---- GEMM1 with fused V construction (one column g = t per thread) ----
    const float xv = xl[t], sv = sl[t];
    float dS0 = 0.f, dS1 = 0.f, xS0 = 0.f, xS1 = 0.f;
    f32x4 acc[8];
    #pragma unroll
    for (int j = 0; j < 8; ++j) acc[j] = (f32x4){0.f, 0.f, 0.f, 0.f};

    const int swz = ((t >> 1) & 3) << 4;
    const int nA  = m * 16 + (l & 15);
    const int aSw = (nA & 7) << 4;

    #pragma unroll 1
    for (int strip = 0; strip < 16; ++strip) {
        const int f0 = strip * 32;
        char* vt = smem + VT_BASE + ((strip & 1) << 15);
        #pragma unroll
        for (int ko = 0; ko < 4; ++ko) {
            float4 xf0 = ((const float4*)xl)[(f0 >> 2) + ko * 2];
            float4 xf1 = ((const float4*)xl)[(f0 >> 2) + ko * 2 + 1];
            float4 sf0 = ((const float4*)sl)[(f0 >> 2) + ko * 2];
            float4 sf1 = ((const float4*)sl)[(f0 >> 2) + ko * 2 + 1];
            const float xf[8] = {xf0.x, xf0.y, xf0.z, xf0.w, xf1.x, xf1.y, xf1.z, xf1.w};
            const float sf[8] = {sf0.x, sf0.y, sf0.z, sf0.w, sf1.x, sf1.y, sf1.z, sf1.w};
            unsigned pk[4];
            float vprev = 0.f;
            #pragma unroll
            for (int i = 0; i < 8; ++i) {
                float r = sf[i] * xv + xf[i] * sv;
                float a = vsqrtf(fabsf(r));
                float v = copysignf(a, r);
                if (i & 1) {
                    dS1 += a; xS1 += xf[i] * v;
                    pk[i >> 1] = cvt_pk_bf16(vprev, v);
                } else {
                    dS0 += a; xS0 += xf[i] * v;
                    vprev = v;
                }
            }
            uint4 u; u.x = pk[0]; u.y = pk[1]; u.z = pk[2]; u.w = pk[3];
            *(uint4*)(vt + t * 64 + ((ko * 16) ^ swz)) = u;
        }
        __syncthreads();
        // MFMA: wave (m, gsb) -> C[n in m-half][g in gsb*128..+128]
        short8 afrag = *(const short8*)(smem + nA * 1024 +
                        ((f0 * 2 + kol * 16) ^ aSw));
        #pragma unroll
        for (int j = 0; j < 8; ++j) {
            const int g = gsb * 128 + j * 16 + (l & 15);
            short8 bfrag = *(const short8*)(vt + g * 64 +
                            ((kol * 16) ^ (((g >> 1) & 3) << 4)));
            acc[j] = __builtin_amdgcn_mfma_f32_16x16x32_bf16(afrag, bfrag, acc[j], 0, 0, 0);
        }
        // no second barrier: next strip writes the other Vt buffer
    }
    __syncthreads();

    // ---- norm factors into Vt region (dead) ----
    {
        const float ia = 1.f / ((dS0 + dS1) + EPS_NORM);
        ((float*)(smem + VT_BASE))[t] = ia;                 // invD @32768
        ((float*)(smem + VT_BASE + 2048))[t] = (xS0 + xS1) * ia;   // xgx @34816
    }
    __syncthreads();

    // ---- A' = bf16(acc * invD), overwriting A region ----
    {
        const float* invD = (const float*)(smem + VT_BASE);
        #pragma unroll
        for (int j = 0; j < 8; ++j) {
            const int g = gsb * 128 + j * 16 + (l & 15);
            const float iv = invD[g];
            #pragma unroll
            for (int r = 0; r < 4; ++r) {
                const int n = m * 16 + (l >> 4) * 4 + r;
                *(unsigned short*)(smem + n * 1024 + ((2 * g) ^ ((n & 7) << 4))) =
                    (unsigned short)cvt_pk_bf16(acc[j][r] * iv, 0.f);
            }
        }
    }
    __syncthreads();

    // ---- phase 3 MFMA: nbh[n][de] = A'[n][g] * w1t[de][g]; h via sparse x-row ----
    f32x4 acc3 = (f32x4){0.f, 0.f, 0.f, 0.f};
    f32x4 acch = (f32x4){0.f, 0.f, 0.f, 0.f};
    {
        const int de = gsb * 16 + (l & 15);
        const unsigned short* wtp = w1t + ((size_t)(k * 64 + de) * 512) + kol * 8;
        const float* xgx = (const float*)(smem + VT_BASE + 2048);
        #pragma unroll 2
        for (int ks = 0; ks < 16; ++ks) {
            short8 bfrag = *(const short8*)(wtp + ks * 32);
            short8 af = *(const short8*)(smem + nA * 1024 +
                        ((ks * 64 + kol * 16) ^ aSw));
            acc3 = __builtin_amdgcn_mfma_f32_16x16x32_bf16(af, bfrag, acc3, 0, 0, 0);
            if (m == 0) {
                short8 afh = {0, 0, 0, 0, 0, 0, 0, 0};
                if ((l & 15) == 0) {
                    float4 p0 = *(const float4*)(xgx + ks * 32 + kol * 8);
                    float4 p1 = *(const float4*)(xgx + ks * 32 + kol * 8 + 4);
                    uint4 pk;
                    pk.x = cvt_pk_bf16(p0.x, p0.y); pk.y = cvt_pk_bf16(p0.z, p0.w);
                    pk.z = cvt_pk_bf16(p1.x, p1.y); pk.w = cvt_pk_bf16(p1.z, p1.w);
                    __builtin_memcpy(&afh, &pk, 16);
                }
                acch = __builtin_amdgcn_mfma_f32_16x16x32_bf16(afh, bfrag, acch, 0, 0, 0);
            }
        }
    }

    // ---- nbh BN per d=gsb over (n,e): cross-wave-pair reduction ----
    float* redst = (float*)(smem + 36864);        // [8 waves][2]
    float* pnb   = (float*)(smem + 36928);        // [2 m][4 d][16 e]
    {
        float vals[4];
        float s1 = 0.f, s2 = 0.f;
        #pragma unroll
        for (int r = 0; r < 4; ++r) {
            float v = acc3[r];
            vals[r] = v; s1 += v; s2 += v * v;
        }
        #pragma unroll
        for (int off = 32; off >= 1; off >>= 1) {
            s1 += __shfl_xor(s1, off);
            s2 += __shfl_xor(s2, off);
        }
        if (l == 0) { redst[w * 2] = s1; redst[w * 2 + 1] = s2; }
        __syncthreads();
        const float S1 = redst[w * 2]     + redst[(w ^ 1) * 2];
        const float S2 = redst[w * 2 + 1] + redst[(w ^ 1) * 2 + 1];
        const float mean = S1 * (1.f / 512.f);
        const float var  = S2 * (1.f / 512.f) - mean * mean;
        const float An   = g1[k * C1 + gsb] * rsqrtf(var + EPS_BN);
        const float Bn   = b1[k * C1 + gsb] - mean * An;
        float nbse = 0.f;
        #pragma unroll
        for (int r = 0; r < 4; ++r) nbse += softsignf(vals[r] * An + Bn);
        nbse += __shfl_xor(nbse, 16);   // reduce over n-groups (l>>4)
        nbse += __shfl_xor(nbse, 32);
        if (l < 16) pnb[m * 64 + gsb * 16 + l] = nbse;

        if (m == 0 && l < 16) {         // h output: x-row of acch
            float hv = acch[0];
            h_raw[pair * 64 + gsb * 16 + l] = hv;
            float t1 = hv, t2 = hv * hv;
            #pragma unroll
            for (int off = 1; off <= 8; off <<= 1) {
                t1 += __shfl_xor(t1, off);
                t2 += __shfl_xor(t2, off);
            }
            if (l == 0) {
                atomicAdd(&hsum[k * 4 + gsb], t1);
                atomicAdd(&hsum[8 + k * 4 + gsb], t2);
            }
        }
    }
    __syncthreads();
    if (t < 64) nbs_out[pair * 64 + t] = pnb[t] + pnb[64 + t];
}

// ---------------------------------------------------------------------------
// Kernel 2: per (b,k) wave: softsign(bn(h)) via hsum, fadj2 (16x16), xg2,
// W2 -> h2_raw; accumulates global h2 BN stats into h2sum via atomics.
// ---------------------------------------------------------------------------
__global__ __launch_bounds__(256) void k_stage2(
    const float* __restrict__ h_rawg, const float* __restrict__ nbsg,
    const float* __restrict__ hsum,
    const float* __restrict__ g1, const float* __restrict__ b1,
    const float* __restrict__ W2,
    float* __restrict__ h2_raw, float* __restrict__ h2sum)
{
    __shared__ float hl[4][64], nl[4][64], fl[4][256], xg2l[4][64];
    const int t = threadIdx.x, wv = t >> 6, l = t & 63;
    const int pair = blockIdx.x * 4 + wv;
    const int k = pair & 1;
    const int d = l >> 4;
    {
        const float S1 = hsum[k * 4 + d], S2 = hsum[8 + k * 4 + d];
        const float mean = S1 * (1.f / 8192.f);
        const float var  = S2 * (1.f / 8192.f) - mean * mean;
        const float A = g1[k * 4 + d] * rsqrtf(var + EPS_BN);
        const float Bc = b1[k * 4 + d] - mean * A;
        float hv = h_rawg[pair * 64 + l];
        hl[wv][l] = softsignf(hv * A + Bc);
        nl[wv][l] = nbsg[pair * 64 + l];
    }
    __syncthreads();
    const int gcol = l & 15;
    float raw[4];
    #pragma unroll
    for (int j = 0; j < 4; ++j) {
        const int idx = l + 64 * j;       // idx = f*16+g (g == gcol)
        const int f = idx >> 4;
        float a = 0.f;
        #pragma unroll
        for (int c = 0; c < 4; ++c) a += hl[wv][c * 16 + f] * nl[wv][c * 16 + gcol];
        raw[j] = a;
        fl[wv][idx] = a;
    }
    __syncthreads();
    float w4[4]; float Dp = 0.f;
    #pragma unroll
    for (int j = 0; j < 4; ++j) {
        const int idx = l + 64 * j;
        const int f = idx >> 4;
        float v = raw[j] + fl[wv][gcol * 16 + f];   // symmetrize
        float a = vsqrtf(fabsf(v));
        Dp += a;
        w4[j] = copysignf(a, v);
    }
    Dp += __shfl_xor(Dp, 16);
    Dp += __shfl_xor(Dp, 32);
    const float invD = 1.f / (Dp + EPS_NORM);
    __syncthreads();
    #pragma unroll
    for (int j = 0; j < 4; ++j) fl[wv][l + 64 * j] = w4[j] * invD;
    __syncthreads();
    {
        const int c = l >> 4;
        float a = 0.f;
        #pragma unroll
        for (int f = 0; f < 16; ++f) a += hl[wv][c * 16 + f] * fl[wv][f * 16 + gcol];
        xg2l[wv][c * 16 + gcol] = a;
    }
    __syncthreads();
    if (l < 32) {
        const float* W2p = W2 + k * (C2 * C1 * F1) + l * (C1 * F1);
        float a = 0.f;
        #pragma unroll
        for (int i = 0; i < 64; ++i) a += xg2l[wv][i] * W2p[i];
        h2_raw[pair * 32 + l] = a;
        atomicAdd(&h2sum[k * 32 + l], a);
        atomicAdd(&h2sum[64 + k * 32 + l], a * a);
    }
}

// ---------------------------------------------------------------------------
// Kernel 3: per-b classifier: softsign(bn(h2)) via h2sum -> relu(64x32) -> 32x40
// ---------------------------------------------------------------------------
__global__ __launch_bounds__(64) void k_cls(
    const float* __restrict__ h2_raw, const float* __restrict__ h2sum,
    const float* __restrict__ g2, const float* __restrict__ b2,
    const float* __restrict__ Wc1, const float* __restrict__ bc1,
    const float* __restrict__ Wc2, const float* __restrict__ bc2,
    float* __restrict__ out)
{
    __shared__ float flat[64];
    __shared__ float hid[32];
    const int b = blockIdx.x, l = threadIdx.x;
    const int k = l >> 5, d = l & 31;     // flat index = k*32+d = l
    {
        const float S1 = h2sum[l], S2 = h2sum[64 + l];
        const float mean = S1 * (1.f / 512.f);
        const float var  = S2 * (1.f / 512.f) - mean * mean;
        const float A = g2[l] * rsqrtf(var + EPS_BN);
        const float Bc = b2[l] - mean * A;
        float v = h2_raw[(b * 2 + k) * 32 + d];
        flat[l] = softsignf(v * A + Bc);
    }
    __syncthreads();
    if (l < 32) {
        float a = bc1[l];
        #pragma unroll
        for (int i = 0; i < 64; ++i) a += flat[i] * Wc1[i * 32 + l];
        hid[l] = fmaxf(a, 0.f);
    }
    __syncthreads();
    if (l < NCLS) {
        float a = bc2[l];
        #pragma unroll
        for (int j = 0; j < 32; ++j) a += hid[j] * Wc2[j * NCLS + l];
        out[b * NCLS + l] = a;
    }
}

// ---------------------------------------------------------------------------
extern "C" void kernel_launch(void* const* d_in, const int* in_sizes, int n_in,
                              void* d_out, int out_size, void* d_ws, size_t ws_size,
                              hipStream_t stream)
{
    const float* x   = (const float*)d_in[0];
    const float* nbg = (const float*)d_in[1];
    const float* W1  = (const float*)d_in[2];
    const float* g1  = (const float*)d_in[3];
    const float* b1  = (const float*)d_in[4];
    const float* W2  = (const float*)d_in[5];
    const float* g2  = (const float*)d_in[6];
    const float* b2  = (const float*)d_in[7];
    const float* Wc1 = (const float*)d_in[8];
    const float* bc1 = (const float*)d_in[9];
    const float* Wc2 = (const float*)d_in[10];
    const float* bc2 = (const float*)d_in[11];
    float* out = (float*)d_out;
    float* ws  = (float*)d_ws;

    // workspace layout (floats):
    float* h_raw  = ws;                   // B*K*64 = 65536
    float* nbs    = ws + 65536;           // B*K*64 = 65536
    float* h2_raw = ws + 131072;          // B*K*32 = 32768 (131072 B)
    float* stats  = ws + 163840;          // hsum[16] + h2sum[128]
    float* hsum   = stats;
    float* h2sum  = stats + 16;
    // w1t (bf16, 2*64*512 ushorts = 131072 B) aliases h2_raw: consumed by
    // k_main before k_stage2 writes h2_raw (stream-ordered).
    unsigned short* w1t = (unsigned short*)h2_raw;

    hipLaunchKernelGGL(k_prep,   dim3(256),             dim3(256), 0, stream, W1, w1t, stats);
    hipLaunchKernelGGL(k_main,   dim3(B_SZ * KHOP),     dim3(512), SMEM_MAIN, stream,
                       x, nbg, w1t, g1, b1, h_raw, nbs, hsum);
    hipLaunchKernelGGL(k_stage2, dim3(B_SZ * KHOP / 4), dim3(256), 0, stream,
                       h_raw, nbs, hsum, g1, b1, W2, h2_raw, h2sum);
    hipLaunchKernelGGL(k_cls,    dim3(B_SZ),            dim3(64), 0, stream,
                       h2_raw, h2sum, g2, b2, Wc1, bc1, Wc2, bc2, out);
}

// Round 7
// 262.128 us; speedup vs baseline: 1.2594x; 1.1512x over previous
//
#include <hip/hip_runtime.h>
#include <hip/hip_bf16.h>

#define B_SZ 512
#define KHOP 2
#define NNB  32
#define F0   512
#define C1   4
#define F1   16
#define C2   32
#define NCLS 40

#define EPS_BN   1e-5f
#define EPS_NORM 1e-7f

typedef __attribute__((ext_vector_type(8))) short short8;
typedef __attribute__((ext_vector_type(4))) float f32x4;

__device__ __forceinline__ float softsignf(float v) { return v / (1.0f + fabsf(v)); }

// HW packed f32->bf16 (RNE). lo -> bits[15:0], hi -> bits[31:16].
__device__ __forceinline__ unsigned cvt_pk_bf16(float lo, float hi) {
    unsigned r;
    asm("v_cvt_pk_bf16_f32 %0, %1, %2" : "=v"(r) : "v"(lo), "v"(hi));
    return r;
}

// Single-instruction sqrt (~1 ulp, fine for our threshold).
__device__ __forceinline__ float vsqrtf(float x) {
    float r;
    asm("v_sqrt_f32 %0, %1" : "=v"(r) : "v"(x));
    return r;
}

// ---------------------------------------------------------------------------
// Prep: W1 (K,C1,1,F0,F1) fp32 -> w1t bf16 [k][de=d*16+e][g]; also zeroes the
// stats accumulators (hsum/h2sum).
// ---------------------------------------------------------------------------
__global__ __launch_bounds__(256) void k_prep(const float* __restrict__ W1,
                                              unsigned short* __restrict__ w1t,
                                              float* __restrict__ stats)
{
    const int idx = blockIdx.x * 256 + threadIdx.x;   // [0, 65536)
    if (blockIdx.x == 0 && threadIdx.x < 144) stats[threadIdx.x] = 0.f;
    const int g  = idx & 511;
    const int de = (idx >> 9) & 63;
    const int kk = idx >> 15;
    const int d = de >> 4, e = de & 15;
    w1t[idx] = (unsigned short)cvt_pk_bf16(W1[((size_t)((kk * 4 + d) * 512) + g) * 16 + e], 0.f);
}

// ---------------------------------------------------------------------------
// Kernel 1: per (b,k) block, 512 threads (8 waves).
// GEMM1 B-fragments (V columns) are built IN-REGISTER per wave -> no Vt LDS
// tile, no per-strip barriers. Wave w owns C[n 0..31][g w*64..w*64+63].
// LDS (53248 B = 52 KiB):
//   [0,32768)      A: nb bf16 [32 n][512 f], byte = n*1024 + (2f ^ ((n&7)<<4))
//                  -> after GEMM1 overwritten by A' = xg bf16 [32 n][512 g]
//   [32768,49152)  scratch: phase-0 s-partials fp32[8][512];
//                  later xgx fp32[512] @32768, redst[16] @34816, pnb[128] @34880
//   [49152,51200)  xl fp32[512]
//   [51200,53248)  sl fp32[512]
// ---------------------------------------------------------------------------
#define SCR_BASE 32768
#define SMEM_MAIN 53248

__global__ __launch_bounds__(512, 4) void k_main(
    const float* __restrict__ xg_, const float* __restrict__ nbg,
    const unsigned short* __restrict__ w1t,
    const float* __restrict__ g1, const float* __restrict__ b1,
    float* __restrict__ h_raw, float* __restrict__ nbs_out,
    float* __restrict__ hsum)
{
    extern __shared__ char smem[];
    float* xl = (float*)(smem + 49152);
    float* sl = (float*)(smem + 51200);

    const int t = threadIdx.x;
    const int pair = blockIdx.x;          // b*2 + k
    const int b = pair >> 1, k = pair & 1;
    const int l = t & 63, w = t >> 6;     // 8 waves
    const int gcol = l & 15, kol = l >> 4;
    const float* nbp = nbg + (size_t)pair * (NNB * F0);

    // ---- phase 0: stage nb -> bf16 A (swizzled) + s-partials; load x ----
    {
        const int oct = t & 63, ng = t >> 6;   // 64 f-octets x 8 n-groups
        const int f0s = oct * 8;
        float sp0=0,sp1=0,sp2=0,sp3=0,sp4=0,sp5=0,sp6=0,sp7=0;
        #pragma unroll
        for (int ni = 0; ni < 4; ++ni) {
            const int n = ng * 4 + ni;
            float4 q0 = *(const float4*)(nbp + n * F0 + f0s);
            float4 q1 = *(const float4*)(nbp + n * F0 + f0s + 4);
            sp0 += q0.x; sp1 += q0.y; sp2 += q0.z; sp3 += q0.w;
            sp4 += q1.x; sp5 += q1.y; sp6 += q1.z; sp7 += q1.w;
            uint4 p;
            p.x = cvt_pk_bf16(q0.x, q0.y);
            p.y = cvt_pk_bf16(q0.z, q0.w);
            p.z = cvt_pk_bf16(q1.x, q1.y);
            p.w = cvt_pk_bf16(q1.z, q1.w);
            *(uint4*)(smem + n * 1024 + ((2 * f0s) ^ ((n & 7) << 4))) = p;
        }
        float* part = (float*)(smem + SCR_BASE);   // [8 ng][512 f]
        *(float4*)(part + ng * 512 + f0s)     = make_float4(sp0, sp1, sp2, sp3);
        *(float4*)(part + ng * 512 + f0s + 4) = make_float4(sp4, sp5, sp6, sp7);
        xl[t] = xg_[b * F0 + t];
    }
    __syncthreads();
    {
        const float* part = (const float*)(smem + SCR_BASE);
        float s = 0.f;
        #pragma unroll
        for (int p = 0; p < 8; ++p) s += part[p * 512 + t];
        sl[t] = s;
    }
    __syncthreads();

    // ---- GEMM1: barrier-free; B-frags (V) built in-register ----
    float xgr[4], sgr[4];
    #pragma unroll
    for (int j = 0; j < 4; ++j) {
        const int g = w * 64 + j * 16 + gcol;
        xgr[j] = xl[g];
        sgr[j] = sl[g];
    }
    f32x4 acc[2][4];
    #pragma unroll
    for (int m2 = 0; m2 < 2; ++m2)
        #pragma unroll
        for (int j = 0; j < 4; ++j)
            acc[m2][j] = (f32x4){0.f, 0.f, 0.f, 0.f};
    float dS[4] = {0.f, 0.f, 0.f, 0.f};
    float xS[4] = {0.f, 0.f, 0.f, 0.f};

    const int nA0 = gcol, nA1 = 16 + gcol;
    const int aSw0 = (nA0 & 7) << 4, aSw1 = (nA1 & 7) << 4;

    #pragma unroll 1
    for (int strip = 0; strip < 16; ++strip) {
        const int f0 = strip * 32;
        const int fo = f0 + kol * 8;
        float4 xq0 = *(const float4*)(xl + fo);
        float4 xq1 = *(const float4*)(xl + fo + 4);
        float4 sq0 = *(const float4*)(sl + fo);
        float4 sq1 = *(const float4*)(sl + fo + 4);
        const float xf[8] = {xq0.x, xq0.y, xq0.z, xq0.w, xq1.x, xq1.y, xq1.z, xq1.w};
        const float sf[8] = {sq0.x, sq0.y, sq0.z, sq0.w, sq1.x, sq1.y, sq1.z, sq1.w};
        short8 afrag0 = *(const short8*)(smem + nA0 * 1024 + ((f0 * 2 + kol * 16) ^ aSw0));
        short8 afrag1 = *(const short8*)(smem + nA1 * 1024 + ((f0 * 2 + kol * 16) ^ aSw1));
        #pragma unroll
        for (int j = 0; j < 4; ++j) {
            unsigned pk[4];
            float vprev = 0.f;
            #pragma unroll
            for (int i = 0; i < 8; ++i) {
                float r = xf[i] * sgr[j] + xgr[j] * sf[i];
                float a = vsqrtf(fabsf(r));
                float v = copysignf(a, r);
                dS[j] += a;
                xS[j] += xf[i] * v;
                if (i & 1) pk[i >> 1] = cvt_pk_bf16(vprev, v);
                else       vprev = v;
            }
            short8 bfrag;
            uint4 bp; bp.x = pk[0]; bp.y = pk[1]; bp.z = pk[2]; bp.w = pk[3];
            __builtin_memcpy(&bfrag, &bp, 16);
            acc[0][j] = __builtin_amdgcn_mfma_f32_16x16x32_bf16(afrag0, bfrag, acc[0][j], 0, 0, 0);
            acc[1][j] = __builtin_amdgcn_mfma_f32_16x16x32_bf16(afrag1, bfrag, acc[1][j], 0, 0, 0);
        }
    }

    // ---- column sums over kol groups -> invD, xgx (in-register) ----
    float iv[4], xgxr[4];
    #pragma unroll
    for (int j = 0; j < 4; ++j) {
        float d = dS[j], x = xS[j];
        d += __shfl_xor(d, 16); d += __shfl_xor(d, 32);
        x += __shfl_xor(x, 16); x += __shfl_xor(x, 32);
        iv[j] = 1.f / (d + EPS_NORM);
        xgxr[j] = x * iv[j];
    }
    __syncthreads();   // all A-frag reads done before A'-overwrite

    // xgx row to LDS for the phase-3 h-path
    float* xgx = (float*)(smem + SCR_BASE);
    if (kol == 0) {
        #pragma unroll
        for (int j = 0; j < 4; ++j) xgx[w * 64 + j * 16 + gcol] = xgxr[j];
    }
    // A' = bf16(acc * invD), overwriting A region
    #pragma unroll
    for (int m2 = 0; m2 < 2; ++m2)
        #pragma unroll
        for (int j = 0; j < 4; ++j) {
            const int g = w * 64 + j * 16 + gcol;
            #pragma unroll
            for (int r = 0; r < 4; ++r) {
                const int n = m2 * 16 + kol * 4 + r;
                *(unsigned short*)(smem + n * 1024 + ((2 * g) ^ ((n & 7) << 4))) =
                    (unsigned short)cvt_pk_bf16(acc[m2][j][r] * iv[j], 0.f);
            }
        }
    __syncthreads();

    // ---- phase 3 MFMA: nbh[n][de] = A'[n][g] * w1t[de][g]; h via sparse x-row ----
    const int m3 = w & 1, dsb = w >> 1;
    const int nA = m3 * 16 + gcol;
    const int aSw = (nA & 7) << 4;
    f32x4 acc3 = (f32x4){0.f, 0.f, 0.f, 0.f};
    f32x4 acch = (f32x4){0.f, 0.f, 0.f, 0.f};
    {
        const int de = dsb * 16 + gcol;
        const unsigned short* wtp = w1t + ((size_t)(k * 64 + de) * 512) + kol * 8;
        #pragma unroll 2
        for (int ks = 0; ks < 16; ++ks) {
            short8 bfrag = *(const short8*)(wtp + ks * 32);
            short8 af = *(const short8*)(smem + nA * 1024 +
                        ((ks * 64 + kol * 16) ^ aSw));
            acc3 = __builtin_amdgcn_mfma_f32_16x16x32_bf16(af, bfrag, acc3, 0, 0, 0);
            if (m3 == 0) {
                short8 afh = {0, 0, 0, 0, 0, 0, 0, 0};
                if (gcol == 0) {
                    float4 p0 = *(const float4*)(xgx + ks * 32 + kol * 8);
                    float4 p1 = *(const float4*)(xgx + ks * 32 + kol * 8 + 4);
                    uint4 pk;
                    pk.x = cvt_pk_bf16(p0.x, p0.y); pk.y = cvt_pk_bf16(p0.z, p0.w);
                    pk.z = cvt_pk_bf16(p1.x, p1.y); pk.w = cvt_pk_bf16(p1.z, p1.w);
                    __builtin_memcpy(&afh, &pk, 16);
                }
                acch = __builtin_amdgcn_mfma_f32_16x16x32_bf16(afh, bfrag, acch, 0, 0, 0);
            }
        }
    }

    // ---- nbh BN per d=dsb over (n,e): cross-wave-pair reduction ----
    float* redst = (float*)(smem + 34816);        // [8 waves][2]
    float* pnb   = (float*)(smem + 34880);        // [2 m][4 d][16 e]
    {
        float vals[4];
        float s1 = 0.f, s2 = 0.f;
        #pragma unroll
        for (int r = 0; r < 4; ++r) {
            float v = acc3[r];
            vals[r] = v; s1 += v; s2 += v * v;
        }
        #pragma unroll
        for (int off = 32; off >= 1; off >>= 1) {
            s1 += __shfl_xor(s1, off);
            s2 += __shfl_xor(s2, off);
        }
        if (l == 0) { redst[w * 2] = s1; redst[w * 2 + 1] = s2; }
        __syncthreads();
        const float S1 = redst[w * 2]     + redst[(w ^ 1) * 2];
        const float S2 = redst[w * 2 + 1] + redst[(w ^ 1) * 2 + 1];
        const float mean = S1 * (1.f / 512.f);
        const float var  = S2 * (1.f / 512.f) - mean * mean;
        const float An   = g1[k * C1 + dsb] * rsqrtf(var + EPS_BN);
        const float Bn   = b1[k * C1 + dsb] - mean * An;
        float nbse = 0.f;
        #pragma unroll
        for (int r = 0; r < 4; ++r) nbse += softsignf(vals[r] * An + Bn);
        nbse += __shfl_xor(nbse, 16);   // reduce over n-groups (l>>4)
        nbse += __shfl_xor(nbse, 32);
        if (l < 16) pnb[m3 * 64 + dsb * 16 + l] = nbse;

        if (m3 == 0 && l < 16) {        // h output: x-row of acch
            float hv = acch[0];
            h_raw[pair * 64 + dsb * 16 + l] = hv;
            float t1 = hv, t2 = hv * hv;
            #pragma unroll
            for (int off = 1; off <= 8; off <<= 1) {
                t1 += __shfl_xor(t1, off);
                t2 += __shfl_xor(t2, off);
            }
            if (l == 0) {
                atomicAdd(&hsum[k * 4 + dsb], t1);
                atomicAdd(&hsum[8 + k * 4 + dsb], t2);
            }
        }
    }
    __syncthreads();
    if (t < 64) nbs_out[pair * 64 + t] = pnb[t] + pnb[64 + t];
}

// ---------------------------------------------------------------------------
// Kernel 2: per (b,k) wave: softsign(bn(h)) via hsum, fadj2 (16x16), xg2,
// W2 -> h2_raw; accumulates global h2 BN stats into h2sum via atomics.
// ---------------------------------------------------------------------------
__global__ __launch_bounds__(256) void k_stage2(
    const float* __restrict__ h_rawg, const float* __restrict__ nbsg,
    const float* __restrict__ hsum,
    const float* __restrict__ g1, const float* __restrict__ b1,
    const float* __restrict__ W2,
    float* __restrict__ h2_raw, float* __restrict__ h2sum)
{
    __shared__ float hl[4][64], nl[4][64], fl[4][256], xg2l[4][64];
    const int t = threadIdx.x, wv = t >> 6, l = t & 63;
    const int pair = blockIdx.x * 4 + wv;
    const int k = pair & 1;
    const int d = l >> 4;
    {
        const float S1 = hsum[k * 4 + d], S2 = hsum[8 + k * 4 + d];
        const float mean = S1 * (1.f / 8192.f);
        const float var  = S2 * (1.f / 8192.f) - mean * mean;
        const float A = g1[k * 4 + d] * rsqrtf(var + EPS_BN);
        const float Bc = b1[k * 4 + d] - mean * A;
        float hv = h_rawg[pair * 64 + l];
        hl[wv][l] = softsignf(hv * A + Bc);
        nl[wv][l] = nbsg[pair * 64 + l];
    }
    __syncthreads();
    const int gcol = l & 15;
    float raw[4];
    #pragma unroll
    for (int j = 0; j < 4; ++j) {
        const int idx = l + 64 * j;       // idx = f*16+g (g == gcol)
        const int f = idx >> 4;
        float a = 0.f;
        #pragma unroll
        for (int c = 0; c < 4; ++c) a += hl[wv][c * 16 + f] * nl[wv][c * 16 + gcol];
        raw[j] = a;
        fl[wv][idx] = a;
    }
    __syncthreads();
    float w4[4]; float Dp = 0.f;
    #pragma unroll
    for (int j = 0; j < 4; ++j) {
        const int idx = l + 64 * j;
        const int f = idx >> 4;
        float v = raw[j] + fl[wv][gcol * 16 + f];   // symmetrize
        float a = vsqrtf(fabsf(v));
        Dp += a;
        w4[j] = copysignf(a, v);
    }
    Dp += __shfl_xor(Dp, 16);
    Dp += __shfl_xor(Dp, 32);
    const float invD = 1.f / (Dp + EPS_NORM);
    __syncthreads();
    #pragma unroll
    for (int j = 0; j < 4; ++j) fl[wv][l + 64 * j] = w4[j] * invD;
    __syncthreads();
    {
        const int c = l >> 4;
        float a = 0.f;
        #pragma unroll
        for (int f = 0; f < 16; ++f) a += hl[wv][c * 16 + f] * fl[wv][f * 16 + gcol];
        xg2l[wv][c * 16 + gcol] = a;
    }
    __syncthreads();
    if (l < 32) {
        const float* W2p = W2 + k * (C2 * C1 * F1) + l * (C1 * F1);
        float a = 0.f;
        #pragma unroll
        for (int i = 0; i < 64; ++i) a += xg2l[wv][i] * W2p[i];
        h2_raw[pair * 32 + l] = a;
        atomicAdd(&h2sum[k * 32 + l], a);
        atomicAdd(&h2sum[64 + k * 32 + l], a * a);
    }
}

// ---------------------------------------------------------------------------
// Kernel 3: per-b classifier: softsign(bn(h2)) via h2sum -> relu(64x32) -> 32x40
// ---------------------------------------------------------------------------
__global__ __launch_bounds__(64) void k_cls(
    const float* __restrict__ h2_raw, const float* __restrict__ h2sum,
    const float* __restrict__ g2, const float* __restrict__ b2,
    const float* __restrict__ Wc1, const float* __restrict__ bc1,
    const float* __restrict__ Wc2, const float* __restrict__ bc2,
    float* __restrict__ out)
{
    __shared__ float flat[64];
    __shared__ float hid[32];
    const int b = blockIdx.x, l = threadIdx.x;
    const int k = l >> 5, d = l & 31;     // flat index = k*32+d = l
    {
        const float S1 = h2sum[l], S2 = h2sum[64 + l];
        const float mean = S1 * (1.f / 512.f);
        const float var  = S2 * (1.f / 512.f) - mean * mean;
        const float A = g2[l] * rsqrtf(var + EPS_BN);
        const float Bc = b2[l] - mean * A;
        float v = h2_raw[(b * 2 + k) * 32 + d];
        flat[l] = softsignf(v * A + Bc);
    }
    __syncthreads();
    if (l < 32) {
        float a = bc1[l];
        #pragma unroll
        for (int i = 0; i < 64; ++i) a += flat[i] * Wc1[i * 32 + l];
        hid[l] = fmaxf(a, 0.f);
    }
    __syncthreads();
    if (l < NCLS) {
        float a = bc2[l];
        #pragma unroll
        for (int j = 0; j < 32; ++j) a += hid[j] * Wc2[j * NCLS + l];
        out[b * NCLS + l] = a;
    }
}

// ---------------------------------------------------------------------------
extern "C" void kernel_launch(void* const* d_in, const int* in_sizes, int n_in,
                              void* d_out, int out_size, void* d_ws, size_t ws_size,
                              hipStream_t stream)
{
    const float* x   = (const float*)d_in[0];
    const float* nbg = (const float*)d_in[1];
    const float* W1  = (const float*)d_in[2];
    const float* g1  = (const float*)d_in[3];
    const float* b1  = (const float*)d_in[4];
    const float* W2  = (const float*)d_in[5];
    const float* g2  = (const float*)d_in[6];
    const float* b2  = (const float*)d_in[7];
    const float* Wc1 = (const float*)d_in[8];
    const float* bc1 = (const float*)d_in[9];
    const float* Wc2 = (const float*)d_in[10];
    const float* bc2 = (const float*)d_in[11];
    float* out = (float*)d_out;
    float* ws  = (float*)d_ws;

    // workspace layout (floats):
    float* h_raw  = ws;                   // B*K*64 = 65536
    float* nbs    = ws + 65536;           // B*K*64 = 65536
    float* h2_raw = ws + 131072;          // B*K*32 = 32768 (131072 B)
    float* stats  = ws + 163840;          // hsum[16] + h2sum[128]
    float* hsum   = stats;
    float* h2sum  = stats + 16;
    // w1t (bf16, 2*64*512 ushorts = 131072 B) aliases h2_raw: consumed by
    // k_main before k_stage2 writes h2_raw (stream-ordered).
    unsigned short* w1t = (unsigned short*)h2_raw;

    hipLaunchKernelGGL(k_prep,   dim3(256),             dim3(256), 0, stream, W1, w1t, stats);
    hipLaunchKernelGGL(k_main,   dim3(B_SZ * KHOP),     dim3(512), SMEM_MAIN, stream,
                       x, nbg, w1t, g1, b1, h_raw, nbs, hsum);
    hipLaunchKernelGGL(k_stage2, dim3(B_SZ * KHOP / 4), dim3(256), 0, stream,
                       h_raw, nbs, hsum, g1, b1, W2, h2_raw, h2sum);
    hipLaunchKernelGGL(k_cls,    dim3(B_SZ),            dim3(64), 0, stream,
                       h2_raw, h2sum, g2, b2, Wc1, bc1, Wc2, bc2, out);
}

// Round 9
// 261.078 us; speedup vs baseline: 1.2644x; 1.0040x over previous
//
#include <hip/hip_runtime.h>
#include <hip/hip_bf16.h>

#define B_SZ 512
#define KHOP 2
#define NNB  32
#define F0   512
#define C1   4
#define F1   16
#define C2   32
#define NCLS 40

#define EPS_BN   1e-5f
#define EPS_NORM 1e-7f

typedef __attribute__((ext_vector_type(8))) short short8;
typedef __attribute__((ext_vector_type(4))) float f32x4;
typedef __attribute__((ext_vector_type(2))) float f32x2;

__device__ __forceinline__ float softsignf(float v) { return v / (1.0f + fabsf(v)); }

// HW packed f32->bf16 (RNE). lo -> bits[15:0], hi -> bits[31:16].
__device__ __forceinline__ unsigned cvt_pk_bf16(float lo, float hi) {
    unsigned r;
    asm("v_cvt_pk_bf16_f32 %0, %1, %2" : "=v"(r) : "v"(lo), "v"(hi));
    return r;
}

// Single-instruction sqrt (~1 ulp, fine for our threshold).
__device__ __forceinline__ float vsqrtf(float x) {
    float r;
    asm("v_sqrt_f32 %0, %1" : "=v"(r) : "v"(x));
    return r;
}

// Packed fp32 ops (VOP3P; default op_sel = per-half semantics).
__device__ __forceinline__ f32x2 pk_mul(f32x2 a, f32x2 b) {
    f32x2 d;
    asm("v_pk_mul_f32 %0, %1, %2" : "=v"(d) : "v"(a), "v"(b));
    return d;
}
__device__ __forceinline__ f32x2 pk_fma(f32x2 a, f32x2 b, f32x2 c) {
    f32x2 d;
    asm("v_pk_fma_f32 %0, %1, %2, %3" : "=v"(d) : "v"(a), "v"(b), "v"(c));
    return d;
}
__device__ __forceinline__ f32x2 pk_add(f32x2 a, f32x2 b) {
    f32x2 d;
    asm("v_pk_add_f32 %0, %1, %2" : "=v"(d) : "v"(a), "v"(b));
    return d;
}

// ---------------------------------------------------------------------------
// Prep: W1 (K,C1,1,F0,F1) fp32 -> w1t bf16 [k][de=d*16+e][g]; also zeroes the
// stats accumulators (hsum/h2sum).
// ---------------------------------------------------------------------------
__global__ __launch_bounds__(256) void k_prep(const float* __restrict__ W1,
                                              unsigned short* __restrict__ w1t,
                                              float* __restrict__ stats)
{
    const int idx = blockIdx.x * 256 + threadIdx.x;   // [0, 65536)
    if (blockIdx.x == 0 && threadIdx.x < 144) stats[threadIdx.x] = 0.f;
    const int g  = idx & 511;
    const int de = (idx >> 9) & 63;
    const int kk = idx >> 15;
    const int d = de >> 4, e = de & 15;
    w1t[idx] = (unsigned short)cvt_pk_bf16(W1[((size_t)((kk * 4 + d) * 512) + g) * 16 + e], 0.f);
}

// ---------------------------------------------------------------------------
// Kernel 1: per (b,k) block, 512 threads (8 waves).
// GEMM1 B-fragments (V columns) built IN-REGISTER per wave (no Vt LDS tile,
// no per-strip barriers). Wave w owns C[n 0..31][g w*64..w*64+63].
// V-core uses packed fp32 (pk_mul/pk_fma/pk_add) to halve issue slots.
// LDS (53248 B):
//   [0,32768)      A: nb bf16 [32 n][512 f], byte = n*1024 + (2f ^ ((n&7)<<4))
//                  -> after GEMM1 overwritten by A' = xg bf16 [32 n][512 g]
//   [32768,49152)  scratch: phase-0 s-partials fp32[8][512];
//                  later xgx fp32[512] @32768, redst[16] @34816, pnb[128] @34880
//   [49152,51200)  xl fp32[512]
//   [51200,53248)  sl fp32[512]
// ---------------------------------------------------------------------------
#define SCR_BASE 32768
#define SMEM_MAIN 53248

__global__ __launch_bounds__(512, 4) void k_main(
    const float* __restrict__ xg_, const float* __restrict__ nbg,
    const unsigned short* __restrict__ w1t,
    const float* __restrict__ g1, const float* __restrict__ b1,
    float* __restrict__ h_raw, float* __restrict__ nbs_out,
    float* __restrict__ hsum)
{
    extern __shared__ char smem[];
    float* xl = (float*)(smem + 49152);
    float* sl = (float*)(smem + 51200);

    const int t = threadIdx.x;
    const int pair = blockIdx.x;          // b*2 + k
    const int b = pair >> 1, k = pair & 1;
    const int l = t & 63, w = t >> 6;     // 8 waves
    const int gcol = l & 15, kol = l >> 4;
    const float* nbp = nbg + (size_t)pair * (NNB * F0);

    // ---- phase 0: stage nb -> bf16 A (swizzled) + s-partials (pk_add); x ----
    {
        const int oct = t & 63, ng = t >> 6;   // 64 f-octets x 8 n-groups
        const int f0s = oct * 8;
        f32x2 sp01 = {0.f, 0.f}, sp23 = {0.f, 0.f};
        f32x2 sp45 = {0.f, 0.f}, sp67 = {0.f, 0.f};
        #pragma unroll
        for (int ni = 0; ni < 4; ++ni) {
            const int n = ng * 4 + ni;
            float4 q0 = *(const float4*)(nbp + n * F0 + f0s);
            float4 q1 = *(const float4*)(nbp + n * F0 + f0s + 4);
            const f32x2* q0p = (const f32x2*)&q0;
            const f32x2* q1p = (const f32x2*)&q1;
            sp01 = pk_add(sp01, q0p[0]); sp23 = pk_add(sp23, q0p[1]);
            sp45 = pk_add(sp45, q1p[0]); sp67 = pk_add(sp67, q1p[1]);
            uint4 p;
            p.x = cvt_pk_bf16(q0.x, q0.y);
            p.y = cvt_pk_bf16(q0.z, q0.w);
            p.z = cvt_pk_bf16(q1.x, q1.y);
            p.w = cvt_pk_bf16(q1.z, q1.w);
            *(uint4*)(smem + n * 1024 + ((2 * f0s) ^ ((n & 7) << 4))) = p;
        }
        float* part = (float*)(smem + SCR_BASE);   // [8 ng][512 f]
        *(float4*)(part + ng * 512 + f0s)     = make_float4(sp01.x, sp01.y, sp23.x, sp23.y);
        *(float4*)(part + ng * 512 + f0s + 4) = make_float4(sp45.x, sp45.y, sp67.x, sp67.y);
        xl[t] = xg_[b * F0 + t];
    }
    __syncthreads();
    {
        const float* part = (const float*)(smem + SCR_BASE);
        float s = 0.f;
        #pragma unroll
        for (int p = 0; p < 8; ++p) s += part[p * 512 + t];
        sl[t] = s;
    }
    __syncthreads();

    // ---- GEMM1: barrier-free; B-frags (V) built in-register, pk fp32 ----
    float xgr[4], sgr[4];
    #pragma unroll
    for (int j = 0; j < 4; ++j) {
        const int g = w * 64 + j * 16 + gcol;
        xgr[j] = xl[g];
        sgr[j] = sl[g];
    }
    f32x4 acc[2][4];
    #pragma unroll
    for (int m2 = 0; m2 < 2; ++m2)
        #pragma unroll
        for (int j = 0; j < 4; ++j)
            acc[m2][j] = (f32x4){0.f, 0.f, 0.f, 0.f};
    f32x2 dS2[4], xS2[4];
    #pragma unroll
    for (int j = 0; j < 4; ++j) { dS2[j] = (f32x2){0.f, 0.f}; xS2[j] = (f32x2){0.f, 0.f}; }

    const int nA0 = gcol, nA1 = 16 + gcol;
    const int aSw0 = (nA0 & 7) << 4, aSw1 = (nA1 & 7) << 4;

    #pragma unroll 1
    for (int strip = 0; strip < 16; ++strip) {
        const int f0 = strip * 32;
        const int fo = f0 + kol * 8;
        float4 xq0 = *(const float4*)(xl + fo);
        float4 xq1 = *(const float4*)(xl + fo + 4);
        float4 sq0 = *(const float4*)(sl + fo);
        float4 sq1 = *(const float4*)(sl + fo + 4);
        f32x2 xp[4], sp_[4];
        xp[0] = ((const f32x2*)&xq0)[0]; xp[1] = ((const f32x2*)&xq0)[1];
        xp[2] = ((const f32x2*)&xq1)[0]; xp[3] = ((const f32x2*)&xq1)[1];
        sp_[0] = ((const f32x2*)&sq0)[0]; sp_[1] = ((const f32x2*)&sq0)[1];
        sp_[2] = ((const f32x2*)&sq1)[0]; sp_[3] = ((const f32x2*)&sq1)[1];
        short8 afrag0 = *(const short8*)(smem + nA0 * 1024 + ((f0 * 2 + kol * 16) ^ aSw0));
        short8 afrag1 = *(const short8*)(smem + nA1 * 1024 + ((f0 * 2 + kol * 16) ^ aSw1));
        #pragma unroll
        for (int j = 0; j < 4; ++j) {
            const f32x2 sg2 = {sgr[j], sgr[j]};
            const f32x2 xg2 = {xgr[j], xgr[j]};
            unsigned pkk[4];
            #pragma unroll
            for (int p = 0; p < 4; ++p) {
                f32x2 tt = pk_mul(sp_[p], xg2);
                f32x2 rr = pk_fma(xp[p], sg2, tt);
                float a0 = vsqrtf(fabsf(rr.x));
                float a1 = vsqrtf(fabsf(rr.y));
                dS2[j] = pk_add(dS2[j], (f32x2){a0, a1});
                float v0 = copysignf(a0, rr.x);
                float v1 = copysignf(a1, rr.y);
                xS2[j] = pk_fma(xp[p], (f32x2){v0, v1}, xS2[j]);
                pkk[p] = cvt_pk_bf16(v0, v1);
            }
            short8 bfrag;
            uint4 bp; bp.x = pkk[0]; bp.y = pkk[1]; bp.z = pkk[2]; bp.w = pkk[3];
            __builtin_memcpy(&bfrag, &bp, 16);
            acc[0][j] = __builtin_amdgcn_mfma_f32_16x16x32_bf16(afrag0, bfrag, acc[0][j], 0, 0, 0);
            acc[1][j] = __builtin_amdgcn_mfma_f32_16x16x32_bf16(afrag1, bfrag, acc[1][j], 0, 0, 0);
        }
    }

    // ---- column sums over kol groups -> invD, xgx (in-register) ----
    float iv[4], xgxr[4];
    #pragma unroll
    for (int j = 0; j < 4; ++j) {
        float d = dS2[j].x + dS2[j].y;
        float x = xS2[j].x + xS2[j].y;
        d += __shfl_xor(d, 16); d += __shfl_xor(d, 32);
        x += __shfl_xor(x, 16); x += __shfl_xor(x, 32);
        iv[j] = 1.f / (d + EPS_NORM);
        xgxr[j] = x * iv[j];
    }
    __syncthreads();   // all A-frag reads done before A'-overwrite

    // xgx row to LDS for the phase-3 h-path
    float* xgx = (float*)(smem + SCR_BASE);
    if (kol == 0) {
        #pragma unroll
        for (int j = 0; j < 4; ++j) xgx[w * 64 + j * 16 + gcol] = xgxr[j];
    }
    // A' = bf16(acc * invD), overwriting A region
    #pragma unroll
    for (int m2 = 0; m2 < 2; ++m2)
        #pragma unroll
        for (int j = 0; j < 4; ++j) {
            const int g = w * 64 + j * 16 + gcol;
            #pragma unroll
            for (int r = 0; r < 4; ++r) {
                const int n = m2 * 16 + kol * 4 + r;
                *(unsigned short*)(smem + n * 1024 + ((2 * g) ^ ((n & 7) << 4))) =
                    (unsigned short)cvt_pk_bf16(acc[m2][j][r] * iv[j], 0.f);
            }
        }
    __syncthreads();

    // ---- phase 3 MFMA: nbh[n][de] = A'[n][g] * w1t[de][g]; h via sparse x-row ----
    const int m3 = w & 1, dsb = w >> 1;
    const int nA = m3 * 16 + gcol;
    const int aSw = (nA & 7) << 4;
    f32x4 acc3 = (f32x4){0.f, 0.f, 0.f, 0.f};
    f32x4 acch = (f32x4){0.f, 0.f, 0.f, 0.f};
    {
        const int de = dsb * 16 + gcol;
        const unsigned short* wtp = w1t + ((size_t)(k * 64 + de) * 512) + kol * 8;
        #pragma unroll 2
        for (int ks = 0; ks < 16; ++ks) {
            short8 bfrag = *(const short8*)(wtp + ks * 32);
            short8 af = *(const short8*)(smem + nA * 1024 +
                        ((ks * 64 + kol * 16) ^ aSw));
            acc3 = __builtin_amdgcn_mfma_f32_16x16x32_bf16(af, bfrag, acc3, 0, 0, 0);
            if (m3 == 0) {
                short8 afh = {0, 0, 0, 0, 0, 0, 0, 0};
                if (gcol == 0) {
                    float4 p0 = *(const float4*)(xgx + ks * 32 + kol * 8);
                    float4 p1 = *(const float4*)(xgx + ks * 32 + kol * 8 + 4);
                    uint4 pk;
                    pk.x = cvt_pk_bf16(p0.x, p0.y); pk.y = cvt_pk_bf16(p0.z, p0.w);
                    pk.z = cvt_pk_bf16(p1.x, p1.y); pk.w = cvt_pk_bf16(p1.z, p1.w);
                    __builtin_memcpy(&afh, &pk, 16);
                }
                acch = __builtin_amdgcn_mfma_f32_16x16x32_bf16(afh, bfrag, acch, 0, 0, 0);
            }
        }
    }

    // ---- nbh BN per d=dsb over (n,e): cross-wave-pair reduction ----
    float* redst = (float*)(smem + 34816);        // [8 waves][2]
    float* pnb   = (float*)(smem + 34880);        // [2 m][4 d][16 e]
    {
        float vals[4];
        float s1 = 0.f, s2 = 0.f;
        #pragma unroll
        for (int r = 0; r < 4; ++r) {
            float v = acc3[r];
            vals[r] = v; s1 += v; s2 += v * v;
        }
        #pragma unroll
        for (int off = 32; off >= 1; off >>= 1) {
            s1 += __shfl_xor(s1, off);
            s2 += __shfl_xor(s2, off);
        }
        if (l == 0) { redst[w * 2] = s1; redst[w * 2 + 1] = s2; }
        __syncthreads();
        const float S1 = redst[w * 2]     + redst[(w ^ 1) * 2];
        const float S2 = redst[w * 2 + 1] + redst[(w ^ 1) * 2 + 1];
        const float mean = S1 * (1.f / 512.f);
        const float var  = S2 * (1.f / 512.f) - mean * mean;
        const float An   = g1[k * C1 + dsb] * rsqrtf(var + EPS_BN);
        const float Bn   = b1[k * C1 + dsb] - mean * An;
        float nbse = 0.f;
        #pragma unroll
        for (int r = 0; r < 4; ++r) nbse += softsignf(vals[r] * An + Bn);
        nbse += __shfl_xor(nbse, 16);   // reduce over n-groups (l>>4)
        nbse += __shfl_xor(nbse, 32);
        if (l < 16) pnb[m3 * 64 + dsb * 16 + l] = nbse;

        if (m3 == 0 && l < 16) {        // h output: x-row of acch
            float hv = acch[0];
            h_raw[pair * 64 + dsb * 16 + l] = hv;
            float t1 = hv, t2 = hv * hv;
            #pragma unroll
            for (int off = 1; off <= 8; off <<= 1) {
                t1 += __shfl_xor(t1, off);
                t2 += __shfl_xor(t2, off);
            }
            if (l == 0) {
                atomicAdd(&hsum[k * 4 + dsb], t1);
                atomicAdd(&hsum[8 + k * 4 + dsb], t2);
            }
        }
    }
    __syncthreads();
    if (t < 64) nbs_out[pair * 64 + t] = pnb[t] + pnb[64 + t];
}

// ---------------------------------------------------------------------------
// Kernel 2: per (b,k) wave: softsign(bn(h)) via hsum, fadj2 (16x16), xg2,
// W2 -> h2_raw; accumulates global h2 BN stats into h2sum via atomics.
// ---------------------------------------------------------------------------
__global__ __launch_bounds__(256) void k_stage2(
    const float* __restrict__ h_rawg, const float* __restrict__ nbsg,
    const float* __restrict__ hsum,
    const float* __restrict__ g1, const float* __restrict__ b1,
    const float* __restrict__ W2,
    float* __restrict__ h2_raw, float* __restrict__ h2sum)
{
    __shared__ float hl[4][64], nl[4][64], fl[4][256], xg2l[4][64];
    const int t = threadIdx.x, wv = t >> 6, l = t & 63;
    const int pair = blockIdx.x * 4 + wv;
    const int k = pair & 1;
    const int d = l >> 4;
    {
        const float S1 = hsum[k * 4 + d], S2 = hsum[8 + k * 4 + d];
        const float mean = S1 * (1.f / 8192.f);
        const float var  = S2 * (1.f / 8192.f) - mean * mean;
        const float A = g1[k * 4 + d] * rsqrtf(var + EPS_BN);
        const float Bc = b1[k * 4 + d] - mean * A;
        float hv = h_rawg[pair * 64 + l];
        hl[wv][l] = softsignf(hv * A + Bc);
        nl[wv][l] = nbsg[pair * 64 + l];
    }
    __syncthreads();
    const int gcol = l & 15;
    float raw[4];
    #pragma unroll
    for (int j = 0; j < 4; ++j) {
        const int idx = l + 64 * j;       // idx = f*16+g (g == gcol)
        const int f = idx >> 4;
        float a = 0.f;
        #pragma unroll
        for (int c = 0; c < 4; ++c) a += hl[wv][c * 16 + f] * nl[wv][c * 16 + gcol];
        raw[j] = a;
        fl[wv][idx] = a;
    }
    __syncthreads();
    float w4[4]; float Dp = 0.f;
    #pragma unroll
    for (int j = 0; j < 4; ++j) {
        const int idx = l + 64 * j;
        const int f = idx >> 4;
        float v = raw[j] + fl[wv][gcol * 16 + f];   // symmetrize
        float a = vsqrtf(fabsf(v));
        Dp += a;
        w4[j] = copysignf(a, v);
    }
    Dp += __shfl_xor(Dp, 16);
    Dp += __shfl_xor(Dp, 32);
    const float invD = 1.f / (Dp + EPS_NORM);
    __syncthreads();
    #pragma unroll
    for (int j = 0; j < 4; ++j) fl[wv][l + 64 * j] = w4[j] * invD;
    __syncthreads();
    {
        const int c = l >> 4;
        float a = 0.f;
        #pragma unroll
        for (int f = 0; f < 16; ++f) a += hl[wv][c * 16 + f] * fl[wv][f * 16 + gcol];
        xg2l[wv][c * 16 + gcol] = a;
    }
    __syncthreads();
    if (l < 32) {
        const float* W2p = W2 + k * (C2 * C1 * F1) + l * (C1 * F1);
        float a = 0.f;
        #pragma unroll
        for (int i = 0; i < 64; ++i) a += xg2l[wv][i] * W2p[i];
        h2_raw[pair * 32 + l] = a;
        atomicAdd(&h2sum[k * 32 + l], a);
        atomicAdd(&h2sum[64 + k * 32 + l], a * a);
    }
}

// ---------------------------------------------------------------------------
// Kernel 3: per-b classifier: softsign(bn(h2)) via h2sum -> relu(64x32) -> 32x40
// ---------------------------------------------------------------------------
__global__ __launch_bounds__(64) void k_cls(
    const float* __restrict__ h2_raw, const float* __restrict__ h2sum,
    const float* __restrict__ g2, const float* __restrict__ b2,
    const float* __restrict__ Wc1, const float* __restrict__ bc1,
    const float* __restrict__ Wc2, const float* __restrict__ bc2,
    float* __restrict__ out)
{
    __shared__ float flat[64];
    __shared__ float hid[32];
    const int b = blockIdx.x, l = threadIdx.x;
    const int k = l >> 5, d = l & 31;     // flat index = k*32+d = l
    {
        const float S1 = h2sum[l], S2 = h2sum[64 + l];
        const float mean = S1 * (1.f / 512.f);
        const float var  = S2 * (1.f / 512.f) - mean * mean;
        const float A = g2[l] * rsqrtf(var + EPS_BN);
        const float Bc = b2[l] - mean * A;
        float v = h2_raw[(b * 2 + k) * 32 + d];
        flat[l] = softsignf(v * A + Bc);
    }
    __syncthreads();
    if (l < 32) {
        float a = bc1[l];
        #pragma unroll
        for (int i = 0; i < 64; ++i) a += flat[i] * Wc1[i * 32 + l];
        hid[l] = fmaxf(a, 0.f);
    }
    __syncthreads();
    if (l < NCLS) {
        float a = bc2[l];
        #pragma unroll
        for (int j = 0; j < 32; ++j) a += hid[j] * Wc2[j * NCLS + l];
        out[b * NCLS + l] = a;
    }
}

// ---------------------------------------------------------------------------
extern "C" void kernel_launch(void* const* d_in, const int* in_sizes, int n_in,
                              void* d_out, int out_size, void* d_ws, size_t ws_size,
                              hipStream_t stream)
{
    const float* x   = (const float*)d_in[0];
    const float* nbg = (const float*)d_in[1];
    const float* W1  = (const float*)d_in[2];
    const float* g1  = (const float*)d_in[3];
    const float* b1  = (const float*)d_in[4];
    const float* W2  = (const float*)d_in[5];
    const float* g2  = (const float*)d_in[6];
    const float* b2  = (const float*)d_in[7];
    const float* Wc1 = (const float*)d_in[8];
    const float* bc1 = (const float*)d_in[9];
    const float* Wc2 = (const float*)d_in[10];
    const float* bc2 = (const float*)d_in[11];
    float* out = (float*)d_out;
    float* ws  = (float*)d_ws;

    // workspace layout (floats):
    float* h_raw  = ws;                   // B*K*64 = 65536
    float* nbs    = ws + 65536;           // B*K*64 = 65536
    float* h2_raw = ws + 131072;          // B*K*32 = 32768 (131072 B)
    float* stats  = ws + 163840;          // hsum[16] + h2sum[128]
    float* hsum   = stats;
    float* h2sum  = stats + 16;
    // w1t (bf16, 2*64*512 ushorts = 131072 B) aliases h2_raw: consumed by
    // k_main before k_stage2 writes h2_raw (stream-ordered).
    unsigned short* w1t = (unsigned short*)h2_raw;

    hipLaunchKernelGGL(k_prep,   dim3(256),             dim3(256), 0, stream, W1, w1t, stats);
    hipLaunchKernelGGL(k_main,   dim3(B_SZ * KHOP),     dim3(512), SMEM_MAIN, stream,
                       x, nbg, w1t, g1, b1, h_raw, nbs, hsum);
    hipLaunchKernelGGL(k_stage2, dim3(B_SZ * KHOP / 4), dim3(256), 0, stream,
                       h_raw, nbs, hsum, g1, b1, W2, h2_raw, h2sum);
    hipLaunchKernelGGL(k_cls,    dim3(B_SZ),            dim3(64), 0, stream,
                       h2_raw, h2sum, g2, b2, Wc1, bc1, Wc2, bc2, out);
}